// Round 4
// baseline (607.799 us; speedup 1.0000x reference)
//
#include <hip/hip_runtime.h>
#include <hip/hip_bf16.h>
#include <stdint.h>

// Problem constants (from reference): B=256,P=512,V=8,L=16 -> N=131072, C=128
#define N_NODES 131072
#define C_IN    128
#define HEADS   4
#define DHEAD   128
#define HD      512        // HEADS*DHEAD
#define E_EDGES 655360     // N*5
#define NEG_SLOPE 0.2f
#define NCHUNK  4
#define CHUNK_N (N_NODES / NCHUNK)   // 32768
#define SCAN_B  (N_NODES / 256)      // 512 scan blocks

typedef short bf16x8 __attribute__((ext_vector_type(8)));
typedef float f32x4  __attribute__((ext_vector_type(4)));

__device__ __forceinline__ float bf2f(unsigned short u) {
    unsigned int x = ((unsigned int)u) << 16;
    return __builtin_bit_cast(float, x);
}
__device__ __forceinline__ unsigned short f2bf(float f) {
    unsigned int u = __builtin_bit_cast(unsigned int, f);
    unsigned int r = u + 0x7FFFu + ((u >> 16) & 1u);   // RNE
    return (unsigned short)(r >> 16);
}
__device__ __forceinline__ float lrelu(float v) {
    return v > 0.0f ? v : NEG_SLOPE * v;
}

// xw/y/bias_g/WT2-K live in a PERMUTED 512-col layout (within-head, so the
// head id of storage index s is still s>>7). Storage s (per head, 7 bits:
// P[2] half[2] b[1] e[2]) <-> logical col (2P+b)*16 + half*4 + e. This makes
// gemm1's pass-pair uint4 stores land as 64 B contiguous row-chunks.
// aggregate is elementwise-per-head: code unchanged. gemm2 sums over K with
// BOTH operands permuted identically: dot invariant.
__device__ __forceinline__ int perm512(int s) {
    int w = s >> 7, r = s & 127;
    int P = r >> 5, half = (r >> 3) & 3, b = (r >> 2) & 1, e = r & 3;
    return w * 128 + (2 * P + b) * 16 + half * 4 + e;
}

// ---------------------------------------------------------------------------
// dtype detection: flags[0]=1 if float inputs are bf16 (else fp32);
//                  flags[1]=1 if edge_index is int64 (else int32)
// ---------------------------------------------------------------------------
__global__ void detect_kernel(const unsigned int* p_f, const unsigned int* p_i, int* flags) {
    int lane = threadIdx.x;   // 64 threads
    int cnt = 0;
#pragma unroll
    for (int r = 0; r < 4; r++) {
        unsigned int e = (p_f[lane + 64 * r] >> 7) & 0xFFu;
        cnt += (e >= 110u && e <= 137u) ? 1 : 0;
    }
    int z = 0;
#pragma unroll
    for (int r = 0; r < 2; r++) {
        z += (p_i[2 * (lane + 64 * r) + 1] == 0u) ? 1 : 0;
    }
#pragma unroll
    for (int o = 1; o < 64; o <<= 1) {
        cnt += __shfl_xor(cnt, o, 64);
        z   += __shfl_xor(z, o, 64);
    }
    if (lane == 0) {
        flags[0] = (cnt >= 128) ? 1 : 0;   // 256 bf16 samples, expect ~240 if bf16
        flags[1] = (z == 128) ? 1 : 0;     // all int64 high words zero
    }
}

// W_gat [128,512] -> WT1 in FRAGMENT-MAJOR layout for gemm1's per-wave B regs:
// flat idx = (((g*4 + kk)*64) + l)*8 + e  maps element
//   col = g*16 + (l&15), k = kk*32 + (l>>4)*8 + e   (g=col-group 0..31)
// so frag (g,kk) is 64 lanes x 16 B contiguous -> one coalesced 1 KB load.
__global__ void conv_w1(const void* in, unsigned short* out, const int* flags) {
    int idx = blockIdx.x * blockDim.x + threadIdx.x;   // 65536
    int e = idx & 7;
    int l = (idx >> 3) & 63;
    int t = idx >> 9;                  // g*4 + kk, 0..127
    int kk = t & 3, g = t >> 2;
    int col = g * 16 + (l & 15);
    int k = kk * 32 + (l >> 4) * 8 + e;
    float v = flags[0] ? bf2f(((const unsigned short*)in)[k * HD + col])
                       : ((const float*)in)[k * HD + col];
    out[idx] = f2bf(v);
}

// W_lin [512,128] -> WT2 bf16 [128,512] with K (the 512 dim) PERMUTED to match
// the xw/y storage layout.
__global__ void conv_w2(const void* in, unsigned short* out, const int* flags) {
    int idx = blockIdx.x * blockDim.x + threadIdx.x;   // 65536
    int n = idx >> 9, s = idx & 511;
    int k = perm512(s);
    float v = flags[0] ? bf2f(((const unsigned short*)in)[k * DHEAD + n])
                       : ((const float*)in)[k * DHEAD + n];
    out[idx] = f2bf(v);
}

// att_src/att_dst (512 each, LOGICAL order) + bias_gat (512, PERMUTED order)
// + b_lin (128, logical) -> fp32
__global__ void conv_small(const void* as, const void* ad, const void* bg, const void* bl,
                           float* att_s, float* att_d, float* bias_g, float* b_lin,
                           const int* flags) {
    int i = blockIdx.x * blockDim.x + threadIdx.x;
    bool bf = flags[0] != 0;
    if (i < 512) {
        att_s[i] = bf ? bf2f(((const unsigned short*)as)[i]) : ((const float*)as)[i];
    } else if (i < 1024) {
        int j = i - 512;
        att_d[j] = bf ? bf2f(((const unsigned short*)ad)[j]) : ((const float*)ad)[j];
    } else if (i < 1536) {
        int j = perm512(i - 1024);     // bias stored permuted
        bias_g[i - 1024] = bf ? bf2f(((const unsigned short*)bg)[j]) : ((const float*)bg)[j];
    } else if (i < 1664) {
        int j = i - 1536;
        b_lin[j] = bf ? bf2f(((const unsigned short*)bl)[j]) : ((const float*)bl)[j];
    }
}

// edge_index [2,E] -> src32 [E], dst32 [E]; fused degree histogram
__global__ void conv_edges_hist(const void* in, int* src32, int* dst32, int* deg,
                                const int* flags) {
    int i = blockIdx.x * blockDim.x + threadIdx.x;
    if (i >= 2 * E_EDGES) return;
    int v = flags[1] ? (int)((const long long*)in)[i] : ((const int*)in)[i];
    if (i < E_EDGES) {
        src32[i] = v;
    } else {
        dst32[i - E_EDGES] = v;
        atomicAdd(&deg[v], 1);
    }
}

__global__ void zero_deg(int* deg) {
    int i = blockIdx.x * blockDim.x + threadIdx.x;
    deg[i] = 0;
}

// ---------------------------------------------------------------------------
// Hierarchical exclusive scan of deg[N] -> offv[N] (+cursor copy).
// ---------------------------------------------------------------------------
__global__ void scan_local(const int* __restrict__ deg, int* __restrict__ offv,
                           int* __restrict__ bsums) {
    __shared__ int tmp[256];
    int t = threadIdx.x;
    int g = blockIdx.x * 256 + t;
    int v = deg[g];
    tmp[t] = v;
    __syncthreads();
#pragma unroll
    for (int d = 1; d < 256; d <<= 1) {
        int x = (t >= d) ? tmp[t - d] : 0;
        __syncthreads();
        tmp[t] += x;
        __syncthreads();
    }
    offv[g] = tmp[t] - v;              // exclusive within block
    if (t == 255) bsums[blockIdx.x] = tmp[t];
}

__global__ void scan_bsums(int* bsums) {
    __shared__ int tmp[SCAN_B];
    int t = threadIdx.x;               // 512 threads
    int v = bsums[t];
    tmp[t] = v;
    __syncthreads();
#pragma unroll
    for (int d = 1; d < SCAN_B; d <<= 1) {
        int x = (t >= d) ? tmp[t - d] : 0;
        __syncthreads();
        tmp[t] += x;
        __syncthreads();
    }
    bsums[t] = tmp[t] - v;             // exclusive block bases
}

__global__ void scan_apply(int* __restrict__ offv, const int* __restrict__ bsums,
                           int* __restrict__ cursor) {
    int g = blockIdx.x * 256 + threadIdx.x;
    int v = offv[g] + bsums[blockIdx.x];
    offv[g] = v;
    cursor[g] = v;
}

__global__ void scatter_kernel(const int* src32, const int* dst32, int* cursor, int* csr) {
    int i = blockIdx.x * blockDim.x + threadIdx.x;
    int d = dst32[i];
    int pos = atomicAdd(&cursor[d], 1);
    csr[pos] = src32[i];
}

// ---------------------------------------------------------------------------
// gemm1 fused v4: xw = x @ W_gat (M=131072, K=128, N=512) + fused attention
// logits.
// Post-mortems: v1 85us (barrier/occupancy), v2 145us (latency on strided
// global B), v3 90us: WRITE_SIZE 138->223 MB (1.6x write amplification:
// 32 B row-chunks spread across the whole pass loop get sector-evicted from
// the overcommitted 4 MB L2 before line completion; v2 proved fast completion
// avoids this) + VGPR 224 (2 waves/SIMD).
// v4 = v3 + pass-pair store pipelining: buffer even pass's packed bf16 in
// regs (pk_lo), store a uint4/lane at odd passes into the PERMUTED xw layout
// -> each store instruction writes 16 rows x 64 B contiguous; sectors
// complete instantly. + __launch_bounds__(256,3): VGPR cap ~168, 3 blocks/CU.
// ---------------------------------------------------------------------------
__launch_bounds__(256, 3)
__global__ void gemm1_fused(const void* __restrict__ Ain,
                            const unsigned short* __restrict__ BT2,  // frag-major WT1
                            const float* __restrict__ attS, const float* __restrict__ attD,
                            unsigned short* __restrict__ xw,
                            float* __restrict__ aSrc, float* __restrict__ aDst,
                            const int* __restrict__ flags) {
    __shared__ unsigned short lA[128 * 136];   // 34816 B
    int tid = threadIdx.x;
    int m0 = blockIdx.x * 128;

    // stage A row-strip (128 x 128), fp32->bf16 if needed
    if (flags[0] == 0) {
        const float* Af = (const float*)Ain;
#pragma unroll
        for (int p = 0; p < 16; p++) {
            int l = p * 256 + tid;                  // 4096 float4 chunks
            int r = l >> 5, c = (l & 31) * 4;
            float4 f = *(const float4*)&Af[(size_t)(m0 + r) * C_IN + c];
            unsigned short t4[4] = {f2bf(f.x), f2bf(f.y), f2bf(f.z), f2bf(f.w)};
            *(uint2*)&lA[r * 136 + c] = *(const uint2*)t4;
        }
    } else {
        const unsigned short* Ab = (const unsigned short*)Ain;
#pragma unroll
        for (int p = 0; p < 8; p++) {
            int l = p * 256 + tid;                  // 2048 uint4 chunks
            int r = l >> 4, c = (l & 15) * 8;
            *(uint4*)&lA[r * 136 + c] = *(const uint4*)&Ab[(size_t)(m0 + r) * C_IN + c];
        }
    }
    __syncthreads();   // the ONLY barrier

    int w = tid >> 6, lane = tid & 63;   // wave w = head w
    int lr = lane & 15, half = lane >> 4;

    const float4* attS4 = (const float4*)attS;
    const float4* attD4 = (const float4*)attD;

    float dS[8], dD[8];
#pragma unroll
    for (int i = 0; i < 8; i++) { dS[i] = 0.f; dD[i] = 0.f; }

    // register double-buffer for B fragments (frag-major: coalesced 1 KB/load)
    bf16x8 bbuf[2][4];
#pragma unroll
    for (int kk = 0; kk < 4; kk++)
        bbuf[0][kk] = *(const bf16x8*)&BT2[(((w * 8 + 0) * 4 + kk) << 9) + (lane << 3)];

    uint2 pk_lo[8];    // packed bf16 of the even pass, flushed at the odd pass

#pragma unroll
    for (int p = 0; p < 8; p++) {       // 8 col-passes of 16 within head w
        int cur = p & 1;
        if (p < 7) {
#pragma unroll
            for (int kk = 0; kk < 4; kk++)
                bbuf[cur ^ 1][kk] =
                    *(const bf16x8*)&BT2[(((w * 8 + p + 1) * 4 + kk) << 9) + (lane << 3)];
        }

        f32x4 acc[8];
#pragma unroll
        for (int i = 0; i < 8; i++) acc[i] = (f32x4){0.f, 0.f, 0.f, 0.f};

#pragma unroll
        for (int kk = 0; kk < 4; kk++) {
#pragma unroll
            for (int i = 0; i < 8; i++) {
                bf16x8 af = *(const bf16x8*)&lA[(i * 16 + lr) * 136 + kk * 32 + half * 8];
                acc[i] = __builtin_amdgcn_mfma_f32_16x16x32_bf16(bbuf[cur][kk], af, acc[i], 0, 0, 0);
            }
        }

        // attention dots use LOGICAL cols p*16 + half*4 + {0..3}
        float4 s4 = attS4[w * 32 + p * 4 + half];
        float4 d4 = attD4[w * 32 + p * 4 + half];
#pragma unroll
        for (int i = 0; i < 8; i++) {
            dS[i] += acc[i][0] * s4.x + acc[i][1] * s4.y + acc[i][2] * s4.z + acc[i][3] * s4.w;
            dD[i] += acc[i][0] * d4.x + acc[i][1] * d4.y + acc[i][2] * d4.z + acc[i][3] * d4.w;
        }

        if ((p & 1) == 0) {
            // even pass: pack and hold
#pragma unroll
            for (int i = 0; i < 8; i++) {
                pk_lo[i].x = (unsigned int)f2bf(acc[i][0]) | ((unsigned int)f2bf(acc[i][1]) << 16);
                pk_lo[i].y = (unsigned int)f2bf(acc[i][2]) | ((unsigned int)f2bf(acc[i][3]) << 16);
            }
        } else {
            // odd pass: store pass-pair as uint4 into permuted layout.
            // storage elem offset (within row) = w*128 + P*32 + half*8,
            // holding logical cols (2P)*16+half*4+{0..3} then (2P+1)*16+half*4+{0..3}.
            int P = p >> 1;
#pragma unroll
            for (int i = 0; i < 8; i++) {
                uint4 q;
                q.x = pk_lo[i].x;
                q.y = pk_lo[i].y;
                q.z = (unsigned int)f2bf(acc[i][0]) | ((unsigned int)f2bf(acc[i][1]) << 16);
                q.w = (unsigned int)f2bf(acc[i][2]) | ((unsigned int)f2bf(acc[i][3]) << 16);
                *(uint4*)&xw[(size_t)(m0 + i * 16 + lr) * HD + w * 128 + P * 32 + half * 8] = q;
            }
        }
    }

    // per-head attention-dot reduce over the 4 half-groups
#pragma unroll
    for (int i = 0; i < 8; i++) {
        float ps = dS[i], pd = dD[i];
        ps += __shfl_xor(ps, 16, 64);
        ps += __shfl_xor(ps, 32, 64);
        pd += __shfl_xor(pd, 16, 64);
        pd += __shfl_xor(pd, 32, 64);
        if (half == 0) {
            aSrc[(size_t)(m0 + i * 16 + lr) * HEADS + w] = ps;
            aDst[(size_t)(m0 + i * 16 + lr) * HEADS + w] = pd;
        }
    }
}

// ---------------------------------------------------------------------------
// gemm2: out = y @ W_lin + b_lin  (rows=CHUNK_N, K=512, N=128), BT=[128,512].
// K dim of BOTH operands is in the permuted storage order (dot invariant).
// ---------------------------------------------------------------------------
__launch_bounds__(256)
__global__ void gemm2(const unsigned short* __restrict__ A,
                      const unsigned short* __restrict__ BT,
                      const float* __restrict__ bias,
                      unsigned short* Cbf, float* Cf,
                      const int* __restrict__ flags, long long rowOff) {
    __shared__ unsigned short smem[64 * 136];   // 8704 shorts; carved below
    unsigned short* lA = smem;                  // 64 x 40  = 2560
    unsigned short* lB = smem + 64 * 40;        // 128 x 40 = 5120 (total 7680 < 8704)
    int tid = threadIdx.x;
    int m0 = blockIdx.x * 64;
    int wid = tid >> 6, lane = tid & 63;
    int wr = (wid >> 1) * 32, wc = (wid & 1) * 64;
    int lr = lane & 15, half = lane >> 4;

    f32x4 acc[2][4];
#pragma unroll
    for (int i = 0; i < 2; i++)
#pragma unroll
        for (int j = 0; j < 4; j++) acc[i][j] = (f32x4){0.f, 0.f, 0.f, 0.f};

    for (int k0 = 0; k0 < HD; k0 += 32) {
        {   // stage A 64x32: 256 uint4, one pass
            int r = tid >> 2, c = (tid & 3) * 8;
            *(uint4*)&lA[r * 40 + c] = *(const uint4*)&A[(size_t)(m0 + r) * HD + k0 + c];
        }
#pragma unroll
        for (int p = 0; p < 2; p++) {   // stage B 128x32
            int l = p * 256 + tid;
            int r = l >> 2, c = (l & 3) * 8;
            *(uint4*)&lB[r * 40 + c] = *(const uint4*)&BT[(size_t)r * HD + k0 + c];
        }
        __syncthreads();
        bf16x8 af[2], bfr[4];
#pragma unroll
        for (int i = 0; i < 2; i++)
            af[i] = *(const bf16x8*)&lA[(wr + i * 16 + lr) * 40 + half * 8];
#pragma unroll
        for (int j = 0; j < 4; j++)
            bfr[j] = *(const bf16x8*)&lB[(wc + j * 16 + lr) * 40 + half * 8];
#pragma unroll
        for (int i = 0; i < 2; i++)
#pragma unroll
            for (int j = 0; j < 4; j++)
                acc[i][j] = __builtin_amdgcn_mfma_f32_16x16x32_bf16(af[i], bfr[j], acc[i][j], 0, 0, 0);
        __syncthreads();
    }

    if (flags[0] != 0) {
        // bf16 out: acc+bias -> smem (stride 136) -> coalesced uint4 stores
#pragma unroll
        for (int i = 0; i < 2; i++)
#pragma unroll
            for (int j = 0; j < 4; j++) {
                int gcol = wc + j * 16 + lr;
                float b = bias[gcol];
#pragma unroll
                for (int r = 0; r < 4; r++)
                    smem[(wr + i * 16 + half * 4 + r) * 136 + gcol] = f2bf(acc[i][j][r] + b);
            }
        __syncthreads();
#pragma unroll
        for (int p = 0; p < 2; p++) {
            int l = p * 256 + tid;
            int r = l >> 4, c = (l & 15) * 8;
            *(uint4*)&Cbf[(size_t)(rowOff + m0 + r) * DHEAD + c] = *(const uint4*)&smem[r * 136 + c];
        }
    } else {
#pragma unroll
        for (int i = 0; i < 2; i++)
#pragma unroll
            for (int j = 0; j < 4; j++) {
                int gcol = wc + j * 16 + lr;
                float b = bias[gcol];
#pragma unroll
                for (int r = 0; r < 4; r++) {
                    int grow = m0 + wr + i * 16 + half * 4 + r;
                    Cf[(size_t)(rowOff + grow) * DHEAD + gcol] = acc[i][j][r] + b;
                }
            }
    }
}

// ---------------------------------------------------------------------------
// aggregate: segment softmax + aggregate + bias + ELU -> y bf16 [CHUNK_N,512]
// ONE WAVE PER NODE covering all 4 heads. Lane l holds STORAGE elements
// 8l..8l+7 of the permuted 512-row (uint4); head h = l>>4 still valid since
// the permutation is within-head. bias_g is stored permuted to match.
// ---------------------------------------------------------------------------
__launch_bounds__(256)
__global__ void aggregate(const unsigned short* __restrict__ xw,
                          const float* __restrict__ a_src, const float* __restrict__ a_dst,
                          const int* __restrict__ off, const int* __restrict__ deg,
                          const int* __restrict__ csr, const float* __restrict__ bias_g,
                          unsigned short* __restrict__ y, int nodeBase) {
    int local = blockIdx.x * 4 + (threadIdx.x >> 6);   // node within chunk
    int node = nodeBase + local;
    int l = threadIdx.x & 63;
    int h = l >> 4;                    // head of this lane's 8 elements
    int ebase = l * 8;                 // element offset in the 512-row
    int o = off[node], dn = deg[node];
    float ad = a_dst[node * HEADS + h];

    float acc[8];
    float denom;
    {   // self loop
        float w = __expf(lrelu(a_src[node * HEADS + h] + ad));
        uint4 q = *(const uint4*)&xw[(size_t)node * HD + ebase];
        const unsigned short* u = (const unsigned short*)&q;
        denom = w;
#pragma unroll
        for (int k = 0; k < 8; k++) acc[k] = w * bf2f(u[k]);
    }

    for (int e0 = 0; e0 < dn; e0 += 8) {
        int   idx[8];
        float as[8];
        uint4 px[8];
#pragma unroll
        for (int b = 0; b < 8; b++)
            idx[b] = (e0 + b < dn) ? csr[o + e0 + b] : node;
#pragma unroll
        for (int b = 0; b < 8; b++)
            as[b] = a_src[idx[b] * HEADS + h];
#pragma unroll
        for (int b = 0; b < 8; b++)
            px[b] = *(const uint4*)&xw[(size_t)idx[b] * HD + ebase];
#pragma unroll
        for (int b = 0; b < 8; b++) {
            float w = (e0 + b < dn) ? __expf(lrelu(as[b] + ad)) : 0.0f;
            denom += w;
            const unsigned short* u = (const unsigned short*)&px[b];
#pragma unroll
            for (int k = 0; k < 8; k++) acc[k] += w * bf2f(u[k]);
        }
    }

    float inv = 1.0f / (denom + 1e-16f);
    unsigned short outp[8];
#pragma unroll
    for (int k = 0; k < 8; k++) {
        float v = acc[k] * inv + bias_g[ebase + k];
        v = v > 0.f ? v : (__expf(v) - 1.0f);   // ELU
        outp[k] = f2bf(v);
    }
    *(uint4*)&y[(size_t)local * HD + ebase] = *(const uint4*)outp;
}

extern "C" void kernel_launch(void* const* d_in, const int* in_sizes, int n_in,
                              void* d_out, int out_size, void* d_ws, size_t ws_size,
                              hipStream_t stream) {
    char* ws = (char*)d_ws;
    size_t wsoff = 0;
    auto alloc = [&](size_t bytes) -> char* {
        char* p = ws + wsoff;
        wsoff += (bytes + 255) & ~(size_t)255;
        return p;
    };

    int*            flags  = (int*)           alloc(256);
    unsigned short* WT1    = (unsigned short*)alloc((size_t)HD * C_IN * 2);        // 128 KB
    unsigned short* WT2    = (unsigned short*)alloc((size_t)DHEAD * HD * 2);       // 128 KB
    float*          attS   = (float*)         alloc(HD * 4);
    float*          attD   = (float*)         alloc(HD * 4);
    float*          biasG  = (float*)         alloc(HD * 4);
    float*          bLin   = (float*)         alloc(DHEAD * 4);
    int*            src32  = (int*)           alloc((size_t)E_EDGES * 4);          // 2.6 MB
    int*            dst32  = (int*)           alloc((size_t)E_EDGES * 4);          // 2.6 MB
    int*            deg    = (int*)           alloc((size_t)N_NODES * 4);          // 0.5 MB
    int*            offv   = (int*)           alloc((size_t)(N_NODES + 1) * 4);    // 0.5 MB
    int*            cursor = (int*)           alloc((size_t)N_NODES * 4);          // 0.5 MB
    int*            csr    = (int*)           alloc((size_t)E_EDGES * 4);          // 2.6 MB
    int*            bsums  = (int*)           alloc((size_t)SCAN_B * 4);           // 2 KB
    float*          aSrc   = (float*)         alloc((size_t)N_NODES * HEADS * 4);  // 2.1 MB
    float*          aDst   = (float*)         alloc((size_t)N_NODES * HEADS * 4);  // 2.1 MB
    unsigned short* xw     = (unsigned short*)alloc((size_t)N_NODES * HD * 2);     // 134.2 MB
    unsigned short* ychunk = (unsigned short*)alloc((size_t)CHUNK_N * HD * 2);     // 33.6 MB
    // total ws use ~182 MB

    const void* patches = d_in[0];
    const void* edges   = d_in[1];
    const void* Wgat    = d_in[2];
    const void* attSrcI = d_in[3];
    const void* attDstI = d_in[4];
    const void* biasGI  = d_in[5];
    const void* WlinI   = d_in[6];
    const void* bLinI   = d_in[7];

    detect_kernel<<<1, 64, 0, stream>>>((const unsigned int*)patches,
                                        (const unsigned int*)edges, flags);

    conv_w1<<<(HD * C_IN) / 256, 256, 0, stream>>>(Wgat, WT1, flags);
    conv_w2<<<(DHEAD * HD) / 256, 256, 0, stream>>>(WlinI, WT2, flags);
    conv_small<<<7, 256, 0, stream>>>(attSrcI, attDstI, biasGI, bLinI,
                                      attS, attD, biasG, bLin, flags);

    zero_deg<<<N_NODES / 256, 256, 0, stream>>>(deg);
    conv_edges_hist<<<(2 * E_EDGES) / 256, 256, 0, stream>>>(edges, src32, dst32, deg, flags);
    scan_local<<<SCAN_B, 256, 0, stream>>>(deg, offv, bsums);
    scan_bsums<<<1, SCAN_B, 0, stream>>>(bsums);
    scan_apply<<<SCAN_B, 256, 0, stream>>>(offv, bsums, cursor);
    scatter_kernel<<<E_EDGES / 256, 256, 0, stream>>>(src32, dst32, cursor, csr);

    // xw = x @ W_gat + fused a_src/a_dst
    gemm1_fused<<<N_NODES / 128, 256, 0, stream>>>(
        patches, WT1, attS, attD, xw, aSrc, aDst, flags);

    // chunked: aggregate -> ychunk -> gemm2 -> d_out rows
    for (int c = 0; c < NCHUNK; c++) {
        int base = c * CHUNK_N;
        aggregate<<<CHUNK_N / 4, 256, 0, stream>>>(xw, aSrc, aDst, offv, deg, csr,
                                                   biasG, ychunk, base);
        gemm2<<<CHUNK_N / 64, 256, 0, stream>>>(
            ychunk, WT2, bLin, (unsigned short*)d_out, (float*)d_out, flags, base);
    }
}

// Round 5
// 449.961 us; speedup vs baseline: 1.3508x; 1.3508x over previous
//
#include <hip/hip_runtime.h>
#include <hip/hip_bf16.h>
#include <stdint.h>

// Problem constants (from reference): B=256,P=512,V=8,L=16 -> N=131072, C=128
#define N_NODES 131072
#define C_IN    128
#define HEADS   4
#define DHEAD   128
#define HD      512        // HEADS*DHEAD
#define E_EDGES 655360     // N*5
#define NEG_SLOPE 0.2f
#define NCHUNK  4
#define CHUNK_N (N_NODES / NCHUNK)   // 32768
#define SCAN_B  (N_NODES / 256)      // 512 scan blocks

typedef short bf16x8 __attribute__((ext_vector_type(8)));
typedef float f32x4  __attribute__((ext_vector_type(4)));

__device__ __forceinline__ float bf2f(unsigned short u) {
    unsigned int x = ((unsigned int)u) << 16;
    return __builtin_bit_cast(float, x);
}
__device__ __forceinline__ unsigned short f2bf(float f) {
    unsigned int u = __builtin_bit_cast(unsigned int, f);
    unsigned int r = u + 0x7FFFu + ((u >> 16) & 1u);   // RNE
    return (unsigned short)(r >> 16);
}
__device__ __forceinline__ float lrelu(float v) {
    return v > 0.0f ? v : NEG_SLOPE * v;
}

// xw/y/bias_g/WT2-K live in a PERMUTED 512-col layout (within-head, so the
// head id of storage index s is still s>>7). Storage s (per head, 7 bits:
// P[2] half[2] b[1] e[2]) <-> logical col (2P+b)*16 + half*4 + e. This makes
// gemm1's pass-pair uint4 stores land as 64 B contiguous row-chunks.
// aggregate is elementwise-per-head: code unchanged. gemm2 sums over K with
// BOTH operands permuted identically: dot invariant.
__device__ __forceinline__ int perm512(int s) {
    int w = s >> 7, r = s & 127;
    int P = r >> 5, half = (r >> 3) & 3, b = (r >> 2) & 1, e = r & 3;
    return w * 128 + (2 * P + b) * 16 + half * 4 + e;
}

// ---------------------------------------------------------------------------
// dtype detection: flags[0]=1 if float inputs are bf16 (else fp32);
//                  flags[1]=1 if edge_index is int64 (else int32)
// ---------------------------------------------------------------------------
__global__ void detect_kernel(const unsigned int* p_f, const unsigned int* p_i, int* flags) {
    int lane = threadIdx.x;   // 64 threads
    int cnt = 0;
#pragma unroll
    for (int r = 0; r < 4; r++) {
        unsigned int e = (p_f[lane + 64 * r] >> 7) & 0xFFu;
        cnt += (e >= 110u && e <= 137u) ? 1 : 0;
    }
    int z = 0;
#pragma unroll
    for (int r = 0; r < 2; r++) {
        z += (p_i[2 * (lane + 64 * r) + 1] == 0u) ? 1 : 0;
    }
#pragma unroll
    for (int o = 1; o < 64; o <<= 1) {
        cnt += __shfl_xor(cnt, o, 64);
        z   += __shfl_xor(z, o, 64);
    }
    if (lane == 0) {
        flags[0] = (cnt >= 128) ? 1 : 0;   // 256 bf16 samples, expect ~240 if bf16
        flags[1] = (z == 128) ? 1 : 0;     // all int64 high words zero
    }
}

// W_gat [128,512] -> WT1 in FRAGMENT-MAJOR layout for gemm1's per-wave B regs:
// flat idx = (((g*4 + kk)*64) + l)*8 + e  maps element
//   col = g*16 + (l&15), k = kk*32 + (l>>4)*8 + e   (g=col-group 0..31)
// so frag (g,kk) is 64 lanes x 16 B contiguous -> one coalesced 1 KB load.
__global__ void conv_w1(const void* in, unsigned short* out, const int* flags) {
    int idx = blockIdx.x * blockDim.x + threadIdx.x;   // 65536
    int e = idx & 7;
    int l = (idx >> 3) & 63;
    int t = idx >> 9;                  // g*4 + kk, 0..127
    int kk = t & 3, g = t >> 2;
    int col = g * 16 + (l & 15);
    int k = kk * 32 + (l >> 4) * 8 + e;
    float v = flags[0] ? bf2f(((const unsigned short*)in)[k * HD + col])
                       : ((const float*)in)[k * HD + col];
    out[idx] = f2bf(v);
}

// W_lin [512,128] -> WT2 bf16 [128,512] with K (the 512 dim) PERMUTED to match
// the xw/y storage layout.
__global__ void conv_w2(const void* in, unsigned short* out, const int* flags) {
    int idx = blockIdx.x * blockDim.x + threadIdx.x;   // 65536
    int n = idx >> 9, s = idx & 511;
    int k = perm512(s);
    float v = flags[0] ? bf2f(((const unsigned short*)in)[k * DHEAD + n])
                       : ((const float*)in)[k * DHEAD + n];
    out[idx] = f2bf(v);
}

// att_src/att_dst (512 each, LOGICAL order) + bias_gat (512, PERMUTED order)
// + b_lin (128, logical) -> fp32
__global__ void conv_small(const void* as, const void* ad, const void* bg, const void* bl,
                           float* att_s, float* att_d, float* bias_g, float* b_lin,
                           const int* flags) {
    int i = blockIdx.x * blockDim.x + threadIdx.x;
    bool bf = flags[0] != 0;
    if (i < 512) {
        att_s[i] = bf ? bf2f(((const unsigned short*)as)[i]) : ((const float*)as)[i];
    } else if (i < 1024) {
        int j = i - 512;
        att_d[j] = bf ? bf2f(((const unsigned short*)ad)[j]) : ((const float*)ad)[j];
    } else if (i < 1536) {
        int j = perm512(i - 1024);     // bias stored permuted
        bias_g[i - 1024] = bf ? bf2f(((const unsigned short*)bg)[j]) : ((const float*)bg)[j];
    } else if (i < 1664) {
        int j = i - 1536;
        b_lin[j] = bf ? bf2f(((const unsigned short*)bl)[j]) : ((const float*)bl)[j];
    }
}

// edge_index [2,E] -> src32 [E], dst32 [E]; fused degree histogram
__global__ void conv_edges_hist(const void* in, int* src32, int* dst32, int* deg,
                                const int* flags) {
    int i = blockIdx.x * blockDim.x + threadIdx.x;
    if (i >= 2 * E_EDGES) return;
    int v = flags[1] ? (int)((const long long*)in)[i] : ((const int*)in)[i];
    if (i < E_EDGES) {
        src32[i] = v;
    } else {
        dst32[i - E_EDGES] = v;
        atomicAdd(&deg[v], 1);
    }
}

__global__ void zero_deg(int* deg) {
    int i = blockIdx.x * blockDim.x + threadIdx.x;
    deg[i] = 0;
}

// ---------------------------------------------------------------------------
// Hierarchical exclusive scan of deg[N] -> offv[N] (+cursor copy).
// ---------------------------------------------------------------------------
__global__ void scan_local(const int* __restrict__ deg, int* __restrict__ offv,
                           int* __restrict__ bsums) {
    __shared__ int tmp[256];
    int t = threadIdx.x;
    int g = blockIdx.x * 256 + t;
    int v = deg[g];
    tmp[t] = v;
    __syncthreads();
#pragma unroll
    for (int d = 1; d < 256; d <<= 1) {
        int x = (t >= d) ? tmp[t - d] : 0;
        __syncthreads();
        tmp[t] += x;
        __syncthreads();
    }
    offv[g] = tmp[t] - v;              // exclusive within block
    if (t == 255) bsums[blockIdx.x] = tmp[t];
}

__global__ void scan_bsums(int* bsums) {
    __shared__ int tmp[SCAN_B];
    int t = threadIdx.x;               // 512 threads
    int v = bsums[t];
    tmp[t] = v;
    __syncthreads();
#pragma unroll
    for (int d = 1; d < SCAN_B; d <<= 1) {
        int x = (t >= d) ? tmp[t - d] : 0;
        __syncthreads();
        tmp[t] += x;
        __syncthreads();
    }
    bsums[t] = tmp[t] - v;             // exclusive block bases
}

__global__ void scan_apply(int* __restrict__ offv, const int* __restrict__ bsums,
                           int* __restrict__ cursor) {
    int g = blockIdx.x * 256 + threadIdx.x;
    int v = offv[g] + bsums[blockIdx.x];
    offv[g] = v;
    cursor[g] = v;
}

__global__ void scatter_kernel(const int* src32, const int* dst32, int* cursor, int* csr) {
    int i = blockIdx.x * blockDim.x + threadIdx.x;
    int d = dst32[i];
    int pos = atomicAdd(&cursor[d], 1);
    csr[pos] = src32[i];
}

// ---------------------------------------------------------------------------
// gemm1 fused v5: xw = x @ W_gat (M=131072, K=128, N=512) + fused attention
// logits.
// Post-mortems: v1 85us (barrier/occupancy). v2 145us (latency on strided
// global B; but proved 8B stores completed quickly don't amplify: WRITE
// 138 MB). v3 90us (WRITE 223 MB: 32B chunks spread across MFMA-separated
// passes get sector-evicted from L2 before line completion; VGPR 224).
// v4 204us (launch_bounds(256,3) capped VGPR at 84 -> scratch spill: FETCH
// 191 MB, WRITE 343 MB — cap rule: ~256/N for 256-thread blocks; unusable).
// v5 = v4 WITHOUT the occupancy cap: clean test of the pass-pair store fix.
// Stores are uint4 covering a pass-pair in the PERMUTED layout -> 16 rows x
// 64 B contiguous per instruction; sectors complete immediately.
// ---------------------------------------------------------------------------
__launch_bounds__(256)
__global__ void gemm1_fused(const void* __restrict__ Ain,
                            const unsigned short* __restrict__ BT2,  // frag-major WT1
                            const float* __restrict__ attS, const float* __restrict__ attD,
                            unsigned short* __restrict__ xw,
                            float* __restrict__ aSrc, float* __restrict__ aDst,
                            const int* __restrict__ flags) {
    __shared__ unsigned short lA[128 * 136];   // 34816 B
    int tid = threadIdx.x;
    int m0 = blockIdx.x * 128;

    // stage A row-strip (128 x 128), fp32->bf16 if needed
    if (flags[0] == 0) {
        const float* Af = (const float*)Ain;
#pragma unroll
        for (int p = 0; p < 16; p++) {
            int l = p * 256 + tid;                  // 4096 float4 chunks
            int r = l >> 5, c = (l & 31) * 4;
            float4 f = *(const float4*)&Af[(size_t)(m0 + r) * C_IN + c];
            unsigned short t4[4] = {f2bf(f.x), f2bf(f.y), f2bf(f.z), f2bf(f.w)};
            *(uint2*)&lA[r * 136 + c] = *(const uint2*)t4;
        }
    } else {
        const unsigned short* Ab = (const unsigned short*)Ain;
#pragma unroll
        for (int p = 0; p < 8; p++) {
            int l = p * 256 + tid;                  // 2048 uint4 chunks
            int r = l >> 4, c = (l & 15) * 8;
            *(uint4*)&lA[r * 136 + c] = *(const uint4*)&Ab[(size_t)(m0 + r) * C_IN + c];
        }
    }
    __syncthreads();   // the ONLY barrier

    int w = tid >> 6, lane = tid & 63;   // wave w = head w
    int lr = lane & 15, half = lane >> 4;

    const float4* attS4 = (const float4*)attS;
    const float4* attD4 = (const float4*)attD;

    float dS[8], dD[8];
#pragma unroll
    for (int i = 0; i < 8; i++) { dS[i] = 0.f; dD[i] = 0.f; }

    // register double-buffer for B fragments (frag-major: coalesced 1 KB/load)
    bf16x8 bbuf[2][4];
#pragma unroll
    for (int kk = 0; kk < 4; kk++)
        bbuf[0][kk] = *(const bf16x8*)&BT2[(((w * 8 + 0) * 4 + kk) << 9) + (lane << 3)];

    uint2 pk_lo[8];    // packed bf16 of the even pass, flushed at the odd pass

#pragma unroll
    for (int p = 0; p < 8; p++) {       // 8 col-passes of 16 within head w
        int cur = p & 1;
        if (p < 7) {
#pragma unroll
            for (int kk = 0; kk < 4; kk++)
                bbuf[cur ^ 1][kk] =
                    *(const bf16x8*)&BT2[(((w * 8 + p + 1) * 4 + kk) << 9) + (lane << 3)];
        }

        f32x4 acc[8];
#pragma unroll
        for (int i = 0; i < 8; i++) acc[i] = (f32x4){0.f, 0.f, 0.f, 0.f};

#pragma unroll
        for (int kk = 0; kk < 4; kk++) {
#pragma unroll
            for (int i = 0; i < 8; i++) {
                bf16x8 af = *(const bf16x8*)&lA[(i * 16 + lr) * 136 + kk * 32 + half * 8];
                acc[i] = __builtin_amdgcn_mfma_f32_16x16x32_bf16(bbuf[cur][kk], af, acc[i], 0, 0, 0);
            }
        }

        // attention dots use LOGICAL cols p*16 + half*4 + {0..3}
        float4 s4 = attS4[w * 32 + p * 4 + half];
        float4 d4 = attD4[w * 32 + p * 4 + half];
#pragma unroll
        for (int i = 0; i < 8; i++) {
            dS[i] += acc[i][0] * s4.x + acc[i][1] * s4.y + acc[i][2] * s4.z + acc[i][3] * s4.w;
            dD[i] += acc[i][0] * d4.x + acc[i][1] * d4.y + acc[i][2] * d4.z + acc[i][3] * d4.w;
        }

        if ((p & 1) == 0) {
            // even pass: pack and hold
#pragma unroll
            for (int i = 0; i < 8; i++) {
                pk_lo[i].x = (unsigned int)f2bf(acc[i][0]) | ((unsigned int)f2bf(acc[i][1]) << 16);
                pk_lo[i].y = (unsigned int)f2bf(acc[i][2]) | ((unsigned int)f2bf(acc[i][3]) << 16);
            }
        } else {
            // odd pass: store pass-pair as uint4 into permuted layout.
            // storage elem offset (within row) = w*128 + P*32 + half*8,
            // holding logical cols (2P)*16+half*4+{0..3} then (2P+1)*16+half*4+{0..3}.
            int P = p >> 1;
#pragma unroll
            for (int i = 0; i < 8; i++) {
                uint4 q;
                q.x = pk_lo[i].x;
                q.y = pk_lo[i].y;
                q.z = (unsigned int)f2bf(acc[i][0]) | ((unsigned int)f2bf(acc[i][1]) << 16);
                q.w = (unsigned int)f2bf(acc[i][2]) | ((unsigned int)f2bf(acc[i][3]) << 16);
                *(uint4*)&xw[(size_t)(m0 + i * 16 + lr) * HD + w * 128 + P * 32 + half * 8] = q;
            }
        }
    }

    // per-head attention-dot reduce over the 4 half-groups
#pragma unroll
    for (int i = 0; i < 8; i++) {
        float ps = dS[i], pd = dD[i];
        ps += __shfl_xor(ps, 16, 64);
        ps += __shfl_xor(ps, 32, 64);
        pd += __shfl_xor(pd, 16, 64);
        pd += __shfl_xor(pd, 32, 64);
        if (half == 0) {
            aSrc[(size_t)(m0 + i * 16 + lr) * HEADS + w] = ps;
            aDst[(size_t)(m0 + i * 16 + lr) * HEADS + w] = pd;
        }
    }
}

// ---------------------------------------------------------------------------
// gemm2: out = y @ W_lin + b_lin  (rows=CHUNK_N, K=512, N=128), BT=[128,512].
// K dim of BOTH operands is in the permuted storage order (dot invariant).
// ---------------------------------------------------------------------------
__launch_bounds__(256)
__global__ void gemm2(const unsigned short* __restrict__ A,
                      const unsigned short* __restrict__ BT,
                      const float* __restrict__ bias,
                      unsigned short* Cbf, float* Cf,
                      const int* __restrict__ flags, long long rowOff) {
    __shared__ unsigned short smem[64 * 136];   // 8704 shorts; carved below
    unsigned short* lA = smem;                  // 64 x 40  = 2560
    unsigned short* lB = smem + 64 * 40;        // 128 x 40 = 5120 (total 7680 < 8704)
    int tid = threadIdx.x;
    int m0 = blockIdx.x * 64;
    int wid = tid >> 6, lane = tid & 63;
    int wr = (wid >> 1) * 32, wc = (wid & 1) * 64;
    int lr = lane & 15, half = lane >> 4;

    f32x4 acc[2][4];
#pragma unroll
    for (int i = 0; i < 2; i++)
#pragma unroll
        for (int j = 0; j < 4; j++) acc[i][j] = (f32x4){0.f, 0.f, 0.f, 0.f};

    for (int k0 = 0; k0 < HD; k0 += 32) {
        {   // stage A 64x32: 256 uint4, one pass
            int r = tid >> 2, c = (tid & 3) * 8;
            *(uint4*)&lA[r * 40 + c] = *(const uint4*)&A[(size_t)(m0 + r) * HD + k0 + c];
        }
#pragma unroll
        for (int p = 0; p < 2; p++) {   // stage B 128x32
            int l = p * 256 + tid;
            int r = l >> 2, c = (l & 3) * 8;
            *(uint4*)&lB[r * 40 + c] = *(const uint4*)&BT[(size_t)r * HD + k0 + c];
        }
        __syncthreads();
        bf16x8 af[2], bfr[4];
#pragma unroll
        for (int i = 0; i < 2; i++)
            af[i] = *(const bf16x8*)&lA[(wr + i * 16 + lr) * 40 + half * 8];
#pragma unroll
        for (int j = 0; j < 4; j++)
            bfr[j] = *(const bf16x8*)&lB[(wc + j * 16 + lr) * 40 + half * 8];
#pragma unroll
        for (int i = 0; i < 2; i++)
#pragma unroll
            for (int j = 0; j < 4; j++)
                acc[i][j] = __builtin_amdgcn_mfma_f32_16x16x32_bf16(af[i], bfr[j], acc[i][j], 0, 0, 0);
        __syncthreads();
    }

    if (flags[0] != 0) {
        // bf16 out: acc+bias -> smem (stride 136) -> coalesced uint4 stores
#pragma unroll
        for (int i = 0; i < 2; i++)
#pragma unroll
            for (int j = 0; j < 4; j++) {
                int gcol = wc + j * 16 + lr;
                float b = bias[gcol];
#pragma unroll
                for (int r = 0; r < 4; r++)
                    smem[(wr + i * 16 + half * 4 + r) * 136 + gcol] = f2bf(acc[i][j][r] + b);
            }
        __syncthreads();
#pragma unroll
        for (int p = 0; p < 2; p++) {
            int l = p * 256 + tid;
            int r = l >> 4, c = (l & 15) * 8;
            *(uint4*)&Cbf[(size_t)(rowOff + m0 + r) * DHEAD + c] = *(const uint4*)&smem[r * 136 + c];
        }
    } else {
#pragma unroll
        for (int i = 0; i < 2; i++)
#pragma unroll
            for (int j = 0; j < 4; j++) {
                int gcol = wc + j * 16 + lr;
                float b = bias[gcol];
#pragma unroll
                for (int r = 0; r < 4; r++) {
                    int grow = m0 + wr + i * 16 + half * 4 + r;
                    Cf[(size_t)(rowOff + grow) * DHEAD + gcol] = acc[i][j][r] + b;
                }
            }
    }
}

// ---------------------------------------------------------------------------
// aggregate: segment softmax + aggregate + bias + ELU -> y bf16 [CHUNK_N,512]
// ONE WAVE PER NODE covering all 4 heads. Lane l holds STORAGE elements
// 8l..8l+7 of the permuted 512-row (uint4); head h = l>>4 still valid since
// the permutation is within-head. bias_g is stored permuted to match.
// ---------------------------------------------------------------------------
__launch_bounds__(256)
__global__ void aggregate(const unsigned short* __restrict__ xw,
                          const float* __restrict__ a_src, const float* __restrict__ a_dst,
                          const int* __restrict__ off, const int* __restrict__ deg,
                          const int* __restrict__ csr, const float* __restrict__ bias_g,
                          unsigned short* __restrict__ y, int nodeBase) {
    int local = blockIdx.x * 4 + (threadIdx.x >> 6);   // node within chunk
    int node = nodeBase + local;
    int l = threadIdx.x & 63;
    int h = l >> 4;                    // head of this lane's 8 elements
    int ebase = l * 8;                 // element offset in the 512-row
    int o = off[node], dn = deg[node];
    float ad = a_dst[node * HEADS + h];

    float acc[8];
    float denom;
    {   // self loop
        float w = __expf(lrelu(a_src[node * HEADS + h] + ad));
        uint4 q = *(const uint4*)&xw[(size_t)node * HD + ebase];
        const unsigned short* u = (const unsigned short*)&q;
        denom = w;
#pragma unroll
        for (int k = 0; k < 8; k++) acc[k] = w * bf2f(u[k]);
    }

    for (int e0 = 0; e0 < dn; e0 += 8) {
        int   idx[8];
        float as[8];
        uint4 px[8];
#pragma unroll
        for (int b = 0; b < 8; b++)
            idx[b] = (e0 + b < dn) ? csr[o + e0 + b] : node;
#pragma unroll
        for (int b = 0; b < 8; b++)
            as[b] = a_src[idx[b] * HEADS + h];
#pragma unroll
        for (int b = 0; b < 8; b++)
            px[b] = *(const uint4*)&xw[(size_t)idx[b] * HD + ebase];
#pragma unroll
        for (int b = 0; b < 8; b++) {
            float w = (e0 + b < dn) ? __expf(lrelu(as[b] + ad)) : 0.0f;
            denom += w;
            const unsigned short* u = (const unsigned short*)&px[b];
#pragma unroll
            for (int k = 0; k < 8; k++) acc[k] += w * bf2f(u[k]);
        }
    }

    float inv = 1.0f / (denom + 1e-16f);
    unsigned short outp[8];
#pragma unroll
    for (int k = 0; k < 8; k++) {
        float v = acc[k] * inv + bias_g[ebase + k];
        v = v > 0.f ? v : (__expf(v) - 1.0f);   // ELU
        outp[k] = f2bf(v);
    }
    *(uint4*)&y[(size_t)local * HD + ebase] = *(const uint4*)outp;
}

extern "C" void kernel_launch(void* const* d_in, const int* in_sizes, int n_in,
                              void* d_out, int out_size, void* d_ws, size_t ws_size,
                              hipStream_t stream) {
    char* ws = (char*)d_ws;
    size_t wsoff = 0;
    auto alloc = [&](size_t bytes) -> char* {
        char* p = ws + wsoff;
        wsoff += (bytes + 255) & ~(size_t)255;
        return p;
    };

    int*            flags  = (int*)           alloc(256);
    unsigned short* WT1    = (unsigned short*)alloc((size_t)HD * C_IN * 2);        // 128 KB
    unsigned short* WT2    = (unsigned short*)alloc((size_t)DHEAD * HD * 2);       // 128 KB
    float*          attS   = (float*)         alloc(HD * 4);
    float*          attD   = (float*)         alloc(HD * 4);
    float*          biasG  = (float*)         alloc(HD * 4);
    float*          bLin   = (float*)         alloc(DHEAD * 4);
    int*            src32  = (int*)           alloc((size_t)E_EDGES * 4);          // 2.6 MB
    int*            dst32  = (int*)           alloc((size_t)E_EDGES * 4);          // 2.6 MB
    int*            deg    = (int*)           alloc((size_t)N_NODES * 4);          // 0.5 MB
    int*            offv   = (int*)           alloc((size_t)(N_NODES + 1) * 4);    // 0.5 MB
    int*            cursor = (int*)           alloc((size_t)N_NODES * 4);          // 0.5 MB
    int*            csr    = (int*)           alloc((size_t)E_EDGES * 4);          // 2.6 MB
    int*            bsums  = (int*)           alloc((size_t)SCAN_B * 4);           // 2 KB
    float*          aSrc   = (float*)         alloc((size_t)N_NODES * HEADS * 4);  // 2.1 MB
    float*          aDst   = (float*)         alloc((size_t)N_NODES * HEADS * 4);  // 2.1 MB
    unsigned short* xw     = (unsigned short*)alloc((size_t)N_NODES * HD * 2);     // 134.2 MB
    unsigned short* ychunk = (unsigned short*)alloc((size_t)CHUNK_N * HD * 2);     // 33.6 MB
    // total ws use ~182 MB

    const void* patches = d_in[0];
    const void* edges   = d_in[1];
    const void* Wgat    = d_in[2];
    const void* attSrcI = d_in[3];
    const void* attDstI = d_in[4];
    const void* biasGI  = d_in[5];
    const void* WlinI   = d_in[6];
    const void* bLinI   = d_in[7];

    detect_kernel<<<1, 64, 0, stream>>>((const unsigned int*)patches,
                                        (const unsigned int*)edges, flags);

    conv_w1<<<(HD * C_IN) / 256, 256, 0, stream>>>(Wgat, WT1, flags);
    conv_w2<<<(DHEAD * HD) / 256, 256, 0, stream>>>(WlinI, WT2, flags);
    conv_small<<<7, 256, 0, stream>>>(attSrcI, attDstI, biasGI, bLinI,
                                      attS, attD, biasG, bLin, flags);

    zero_deg<<<N_NODES / 256, 256, 0, stream>>>(deg);
    conv_edges_hist<<<(2 * E_EDGES) / 256, 256, 0, stream>>>(edges, src32, dst32, deg, flags);
    scan_local<<<SCAN_B, 256, 0, stream>>>(deg, offv, bsums);
    scan_bsums<<<1, SCAN_B, 0, stream>>>(bsums);
    scan_apply<<<SCAN_B, 256, 0, stream>>>(offv, bsums, cursor);
    scatter_kernel<<<E_EDGES / 256, 256, 0, stream>>>(src32, dst32, cursor, csr);

    // xw = x @ W_gat + fused a_src/a_dst
    gemm1_fused<<<N_NODES / 128, 256, 0, stream>>>(
        patches, WT1, attS, attD, xw, aSrc, aDst, flags);

    // chunked: aggregate -> ychunk -> gemm2 -> d_out rows
    for (int c = 0; c < NCHUNK; c++) {
        int base = c * CHUNK_N;
        aggregate<<<CHUNK_N / 4, 256, 0, stream>>>(xw, aSrc, aDst, offv, deg, csr,
                                                   biasG, ychunk, base);
        gemm2<<<CHUNK_N / 64, 256, 0, stream>>>(
            ychunk, WT2, bLin, (unsigned short*)d_out, (float*)d_out, flags, base);
    }
}

// Round 6
// 448.026 us; speedup vs baseline: 1.3566x; 1.0043x over previous
//
#include <hip/hip_runtime.h>
#include <hip/hip_bf16.h>
#include <stdint.h>

// Problem constants (from reference): B=256,P=512,V=8,L=16 -> N=131072, C=128
#define N_NODES 131072
#define C_IN    128
#define HEADS   4
#define DHEAD   128
#define HD      512        // HEADS*DHEAD
#define E_EDGES 655360     // N*5
#define NEG_SLOPE 0.2f
#define NCHUNK  4
#define CHUNK_N (N_NODES / NCHUNK)   // 32768
#define SCAN_B  (N_NODES / 256)      // 512 scan blocks

typedef short bf16x8 __attribute__((ext_vector_type(8)));
typedef float f32x4  __attribute__((ext_vector_type(4)));

__device__ __forceinline__ float bf2f(unsigned short u) {
    unsigned int x = ((unsigned int)u) << 16;
    return __builtin_bit_cast(float, x);
}
__device__ __forceinline__ unsigned short f2bf(float f) {
    unsigned int u = __builtin_bit_cast(unsigned int, f);
    unsigned int r = u + 0x7FFFu + ((u >> 16) & 1u);   // RNE
    return (unsigned short)(r >> 16);
}
__device__ __forceinline__ float lrelu(float v) {
    return v > 0.0f ? v : NEG_SLOPE * v;
}

// xw/y/bias_g/WT2-K live in a PERMUTED 512-col layout (within-head, so the
// head id of storage index s is still s>>7). Storage s (per head, 7 bits:
// P[2] half[2] b[1] e[2]) <-> logical col (2P+b)*16 + half*4 + e. This makes
// gemm1's pass-pair uint4 stores land as 64 B contiguous row-chunks
// (WRITE_SIZE 223->135 MB, amplification eliminated — verified R5).
// aggregate is elementwise-per-head: code unchanged. gemm2 sums over K with
// BOTH operands permuted identically: dot invariant.
__device__ __forceinline__ int perm512(int s) {
    int w = s >> 7, r = s & 127;
    int P = r >> 5, half = (r >> 3) & 3, b = (r >> 2) & 1, e = r & 3;
    return w * 128 + (2 * P + b) * 16 + half * 4 + e;
}

// ---------------------------------------------------------------------------
// dtype detection: flags[0]=1 if float inputs are bf16 (else fp32);
//                  flags[1]=1 if edge_index is int64 (else int32)
// ---------------------------------------------------------------------------
__global__ void detect_kernel(const unsigned int* p_f, const unsigned int* p_i, int* flags) {
    int lane = threadIdx.x;   // 64 threads
    int cnt = 0;
#pragma unroll
    for (int r = 0; r < 4; r++) {
        unsigned int e = (p_f[lane + 64 * r] >> 7) & 0xFFu;
        cnt += (e >= 110u && e <= 137u) ? 1 : 0;
    }
    int z = 0;
#pragma unroll
    for (int r = 0; r < 2; r++) {
        z += (p_i[2 * (lane + 64 * r) + 1] == 0u) ? 1 : 0;
    }
#pragma unroll
    for (int o = 1; o < 64; o <<= 1) {
        cnt += __shfl_xor(cnt, o, 64);
        z   += __shfl_xor(z, o, 64);
    }
    if (lane == 0) {
        flags[0] = (cnt >= 128) ? 1 : 0;   // 256 bf16 samples, expect ~240 if bf16
        flags[1] = (z == 128) ? 1 : 0;     // all int64 high words zero
    }
}

// W_gat [128,512] -> WT1 in FRAGMENT-MAJOR layout for gemm1's per-wave B regs:
// flat idx = (((g*4 + kk)*64) + l)*8 + e  maps element
//   col = g*16 + (l&15), k = kk*32 + (l>>4)*8 + e   (g=col-group 0..31)
// so frag (g,kk) is 64 lanes x 16 B contiguous -> one coalesced 1 KB load.
__global__ void conv_w1(const void* in, unsigned short* out, const int* flags) {
    int idx = blockIdx.x * blockDim.x + threadIdx.x;   // 65536
    int e = idx & 7;
    int l = (idx >> 3) & 63;
    int t = idx >> 9;                  // g*4 + kk, 0..127
    int kk = t & 3, g = t >> 2;
    int col = g * 16 + (l & 15);
    int k = kk * 32 + (l >> 4) * 8 + e;
    float v = flags[0] ? bf2f(((const unsigned short*)in)[k * HD + col])
                       : ((const float*)in)[k * HD + col];
    out[idx] = f2bf(v);
}

// W_lin [512,128] -> WT2 bf16 [128,512] with K (the 512 dim) PERMUTED to match
// the xw/y storage layout.
__global__ void conv_w2(const void* in, unsigned short* out, const int* flags) {
    int idx = blockIdx.x * blockDim.x + threadIdx.x;   // 65536
    int n = idx >> 9, s = idx & 511;
    int k = perm512(s);
    float v = flags[0] ? bf2f(((const unsigned short*)in)[k * DHEAD + n])
                       : ((const float*)in)[k * DHEAD + n];
    out[idx] = f2bf(v);
}

// att_src/att_dst (512 each, LOGICAL order) + bias_gat (512, PERMUTED order)
// + b_lin (128, logical) -> fp32
__global__ void conv_small(const void* as, const void* ad, const void* bg, const void* bl,
                           float* att_s, float* att_d, float* bias_g, float* b_lin,
                           const int* flags) {
    int i = blockIdx.x * blockDim.x + threadIdx.x;
    bool bf = flags[0] != 0;
    if (i < 512) {
        att_s[i] = bf ? bf2f(((const unsigned short*)as)[i]) : ((const float*)as)[i];
    } else if (i < 1024) {
        int j = i - 512;
        att_d[j] = bf ? bf2f(((const unsigned short*)ad)[j]) : ((const float*)ad)[j];
    } else if (i < 1536) {
        int j = perm512(i - 1024);     // bias stored permuted
        bias_g[i - 1024] = bf ? bf2f(((const unsigned short*)bg)[j]) : ((const float*)bg)[j];
    } else if (i < 1664) {
        int j = i - 1536;
        b_lin[j] = bf ? bf2f(((const unsigned short*)bl)[j]) : ((const float*)bl)[j];
    }
}

// edge_index [2,E] -> src32 [E], dst32 [E]; fused degree histogram
__global__ void conv_edges_hist(const void* in, int* src32, int* dst32, int* deg,
                                const int* flags) {
    int i = blockIdx.x * blockDim.x + threadIdx.x;
    if (i >= 2 * E_EDGES) return;
    int v = flags[1] ? (int)((const long long*)in)[i] : ((const int*)in)[i];
    if (i < E_EDGES) {
        src32[i] = v;
    } else {
        dst32[i - E_EDGES] = v;
        atomicAdd(&deg[v], 1);
    }
}

__global__ void zero_deg(int* deg) {
    int i = blockIdx.x * blockDim.x + threadIdx.x;
    deg[i] = 0;
}

// ---------------------------------------------------------------------------
// Hierarchical exclusive scan of deg[N] -> offv[N] (+cursor copy).
// ---------------------------------------------------------------------------
__global__ void scan_local(const int* __restrict__ deg, int* __restrict__ offv,
                           int* __restrict__ bsums) {
    __shared__ int tmp[256];
    int t = threadIdx.x;
    int g = blockIdx.x * 256 + t;
    int v = deg[g];
    tmp[t] = v;
    __syncthreads();
#pragma unroll
    for (int d = 1; d < 256; d <<= 1) {
        int x = (t >= d) ? tmp[t - d] : 0;
        __syncthreads();
        tmp[t] += x;
        __syncthreads();
    }
    offv[g] = tmp[t] - v;              // exclusive within block
    if (t == 255) bsums[blockIdx.x] = tmp[t];
}

__global__ void scan_bsums(int* bsums) {
    __shared__ int tmp[SCAN_B];
    int t = threadIdx.x;               // 512 threads
    int v = bsums[t];
    tmp[t] = v;
    __syncthreads();
#pragma unroll
    for (int d = 1; d < SCAN_B; d <<= 1) {
        int x = (t >= d) ? tmp[t - d] : 0;
        __syncthreads();
        tmp[t] += x;
        __syncthreads();
    }
    bsums[t] = tmp[t] - v;             // exclusive block bases
}

__global__ void scan_apply(int* __restrict__ offv, const int* __restrict__ bsums,
                           int* __restrict__ cursor) {
    int g = blockIdx.x * 256 + threadIdx.x;
    int v = offv[g] + bsums[blockIdx.x];
    offv[g] = v;
    cursor[g] = v;
}

__global__ void scatter_kernel(const int* src32, const int* dst32, int* cursor, int* csr) {
    int i = blockIdx.x * blockDim.x + threadIdx.x;
    int d = dst32[i];
    int pos = atomicAdd(&cursor[d], 1);
    csr[pos] = src32[i];
}

// ---------------------------------------------------------------------------
// gemm1 fused v6: xw = x @ W_gat (M=131072, K=128, N=512) + fused attention
// logits.
// Post-mortems: v1 85us (barrier/occ). v2 145us (latency on strided global
// B). v3 90us (WRITE 223 MB amplification). v4 204us (launch_bounds VGPR cap
// -> spill). v5 74.8us (pass-pair uint4 stores into permuted layout: WRITE
// back to 135 MB — CONFIRMED; but 32 ds_read_b128 per pass vs 32 MFMA: the
// A-tile was re-read from LDS every pass; VGPR 240, 2 waves/SIMD).
// v6: 64-row blocks; A fragments hoisted to registers ONCE (16 bf16x8 = 64
// VGPR), pass loop has ZERO LDS reads: 4 prefetched L2 B-loads + 16 MFMA +
// epilogue. Expected VGPR ~165 (3 waves/SIMD). Store path unchanged from v5.
// ---------------------------------------------------------------------------
__launch_bounds__(256)
__global__ void gemm1_fused(const void* __restrict__ Ain,
                            const unsigned short* __restrict__ BT2,  // frag-major WT1
                            const float* __restrict__ attS, const float* __restrict__ attD,
                            unsigned short* __restrict__ xw,
                            float* __restrict__ aSrc, float* __restrict__ aDst,
                            const int* __restrict__ flags) {
    __shared__ unsigned short lA[64 * 136];   // 17408 B
    int tid = threadIdx.x;
    int m0 = blockIdx.x * 64;

    // stage A row-strip (64 x 128), fp32->bf16 if needed
    if (flags[0] == 0) {
        const float* Af = (const float*)Ain;
#pragma unroll
        for (int p = 0; p < 8; p++) {
            int l = p * 256 + tid;                  // 2048 float4 chunks
            int r = l >> 5, c = (l & 31) * 4;
            float4 f = *(const float4*)&Af[(size_t)(m0 + r) * C_IN + c];
            unsigned short t4[4] = {f2bf(f.x), f2bf(f.y), f2bf(f.z), f2bf(f.w)};
            *(uint2*)&lA[r * 136 + c] = *(const uint2*)t4;
        }
    } else {
        const unsigned short* Ab = (const unsigned short*)Ain;
#pragma unroll
        for (int p = 0; p < 4; p++) {
            int l = p * 256 + tid;                  // 1024 uint4 chunks
            int r = l >> 4, c = (l & 15) * 8;
            *(uint4*)&lA[r * 136 + c] = *(const uint4*)&Ab[(size_t)(m0 + r) * C_IN + c];
        }
    }
    __syncthreads();   // the ONLY barrier

    int w = tid >> 6, lane = tid & 63;   // wave w = head w, 64 rows x 128 cols
    int lr = lane & 15, half = lane >> 4;

    // hoist ALL A fragments for this wave into registers (16 bf16x8 = 64 VGPR)
    // -> the pass loop below does ZERO LDS reads.
    bf16x8 afr[4][4];
#pragma unroll
    for (int i = 0; i < 4; i++)
#pragma unroll
        for (int kk = 0; kk < 4; kk++)
            afr[i][kk] = *(const bf16x8*)&lA[(i * 16 + lr) * 136 + kk * 32 + half * 8];

    const float4* attS4 = (const float4*)attS;
    const float4* attD4 = (const float4*)attD;

    float dS[4], dD[4];
#pragma unroll
    for (int i = 0; i < 4; i++) { dS[i] = 0.f; dD[i] = 0.f; }

    // register double-buffer for B fragments (frag-major: coalesced 1 KB/load)
    bf16x8 bbuf[2][4];
#pragma unroll
    for (int kk = 0; kk < 4; kk++)
        bbuf[0][kk] = *(const bf16x8*)&BT2[(((w * 8 + 0) * 4 + kk) << 9) + (lane << 3)];

    uint2 pk_lo[4];    // packed bf16 of the even pass, flushed at the odd pass

#pragma unroll
    for (int p = 0; p < 8; p++) {       // 8 col-passes of 16 within head w
        int cur = p & 1;
        if (p < 7) {
#pragma unroll
            for (int kk = 0; kk < 4; kk++)
                bbuf[cur ^ 1][kk] =
                    *(const bf16x8*)&BT2[(((w * 8 + p + 1) * 4 + kk) << 9) + (lane << 3)];
        }

        f32x4 acc[4];
#pragma unroll
        for (int i = 0; i < 4; i++) acc[i] = (f32x4){0.f, 0.f, 0.f, 0.f};

#pragma unroll
        for (int kk = 0; kk < 4; kk++)
#pragma unroll
            for (int i = 0; i < 4; i++)
                acc[i] = __builtin_amdgcn_mfma_f32_16x16x32_bf16(bbuf[cur][kk], afr[i][kk], acc[i], 0, 0, 0);

        // attention dots use LOGICAL cols p*16 + half*4 + {0..3}
        float4 s4 = attS4[w * 32 + p * 4 + half];
        float4 d4 = attD4[w * 32 + p * 4 + half];
#pragma unroll
        for (int i = 0; i < 4; i++) {
            dS[i] += acc[i][0] * s4.x + acc[i][1] * s4.y + acc[i][2] * s4.z + acc[i][3] * s4.w;
            dD[i] += acc[i][0] * d4.x + acc[i][1] * d4.y + acc[i][2] * d4.z + acc[i][3] * d4.w;
        }

        if ((p & 1) == 0) {
            // even pass: pack and hold
#pragma unroll
            for (int i = 0; i < 4; i++) {
                pk_lo[i].x = (unsigned int)f2bf(acc[i][0]) | ((unsigned int)f2bf(acc[i][1]) << 16);
                pk_lo[i].y = (unsigned int)f2bf(acc[i][2]) | ((unsigned int)f2bf(acc[i][3]) << 16);
            }
        } else {
            // odd pass: store pass-pair as uint4 into permuted layout.
            // storage elem offset (within row) = w*128 + P*32 + half*8,
            // holding logical cols (2P)*16+half*4+{0..3} then (2P+1)*16+half*4+{0..3}.
            int P = p >> 1;
#pragma unroll
            for (int i = 0; i < 4; i++) {
                uint4 q;
                q.x = pk_lo[i].x;
                q.y = pk_lo[i].y;
                q.z = (unsigned int)f2bf(acc[i][0]) | ((unsigned int)f2bf(acc[i][1]) << 16);
                q.w = (unsigned int)f2bf(acc[i][2]) | ((unsigned int)f2bf(acc[i][3]) << 16);
                *(uint4*)&xw[(size_t)(m0 + i * 16 + lr) * HD + w * 128 + P * 32 + half * 8] = q;
            }
        }
    }

    // per-head attention-dot reduce over the 4 half-groups
#pragma unroll
    for (int i = 0; i < 4; i++) {
        float ps = dS[i], pd = dD[i];
        ps += __shfl_xor(ps, 16, 64);
        ps += __shfl_xor(ps, 32, 64);
        pd += __shfl_xor(pd, 16, 64);
        pd += __shfl_xor(pd, 32, 64);
        if (half == 0) {
            aSrc[(size_t)(m0 + i * 16 + lr) * HEADS + w] = ps;
            aDst[(size_t)(m0 + i * 16 + lr) * HEADS + w] = pd;
        }
    }
}

// ---------------------------------------------------------------------------
// gemm2: out = y @ W_lin + b_lin  (rows=CHUNK_N, K=512, N=128), BT=[128,512].
// K dim of BOTH operands is in the permuted storage order (dot invariant).
// ---------------------------------------------------------------------------
__launch_bounds__(256)
__global__ void gemm2(const unsigned short* __restrict__ A,
                      const unsigned short* __restrict__ BT,
                      const float* __restrict__ bias,
                      unsigned short* Cbf, float* Cf,
                      const int* __restrict__ flags, long long rowOff) {
    __shared__ unsigned short smem[64 * 136];   // 8704 shorts; carved below
    unsigned short* lA = smem;                  // 64 x 40  = 2560
    unsigned short* lB = smem + 64 * 40;        // 128 x 40 = 5120 (total 7680 < 8704)
    int tid = threadIdx.x;
    int m0 = blockIdx.x * 64;
    int wid = tid >> 6, lane = tid & 63;
    int wr = (wid >> 1) * 32, wc = (wid & 1) * 64;
    int lr = lane & 15, half = lane >> 4;

    f32x4 acc[2][4];
#pragma unroll
    for (int i = 0; i < 2; i++)
#pragma unroll
        for (int j = 0; j < 4; j++) acc[i][j] = (f32x4){0.f, 0.f, 0.f, 0.f};

    for (int k0 = 0; k0 < HD; k0 += 32) {
        {   // stage A 64x32: 256 uint4, one pass
            int r = tid >> 2, c = (tid & 3) * 8;
            *(uint4*)&lA[r * 40 + c] = *(const uint4*)&A[(size_t)(m0 + r) * HD + k0 + c];
        }
#pragma unroll
        for (int p = 0; p < 2; p++) {   // stage B 128x32
            int l = p * 256 + tid;
            int r = l >> 2, c = (l & 3) * 8;
            *(uint4*)&lB[r * 40 + c] = *(const uint4*)&BT[(size_t)r * HD + k0 + c];
        }
        __syncthreads();
        bf16x8 af[2], bfr[4];
#pragma unroll
        for (int i = 0; i < 2; i++)
            af[i] = *(const bf16x8*)&lA[(wr + i * 16 + lr) * 40 + half * 8];
#pragma unroll
        for (int j = 0; j < 4; j++)
            bfr[j] = *(const bf16x8*)&lB[(wc + j * 16 + lr) * 40 + half * 8];
#pragma unroll
        for (int i = 0; i < 2; i++)
#pragma unroll
            for (int j = 0; j < 4; j++)
                acc[i][j] = __builtin_amdgcn_mfma_f32_16x16x32_bf16(af[i], bfr[j], acc[i][j], 0, 0, 0);
        __syncthreads();
    }

    if (flags[0] != 0) {
        // bf16 out: acc+bias -> smem (stride 136) -> coalesced uint4 stores
#pragma unroll
        for (int i = 0; i < 2; i++)
#pragma unroll
            for (int j = 0; j < 4; j++) {
                int gcol = wc + j * 16 + lr;
                float b = bias[gcol];
#pragma unroll
                for (int r = 0; r < 4; r++)
                    smem[(wr + i * 16 + half * 4 + r) * 136 + gcol] = f2bf(acc[i][j][r] + b);
            }
        __syncthreads();
#pragma unroll
        for (int p = 0; p < 2; p++) {
            int l = p * 256 + tid;
            int r = l >> 4, c = (l & 15) * 8;
            *(uint4*)&Cbf[(size_t)(rowOff + m0 + r) * DHEAD + c] = *(const uint4*)&smem[r * 136 + c];
        }
    } else {
#pragma unroll
        for (int i = 0; i < 2; i++)
#pragma unroll
            for (int j = 0; j < 4; j++) {
                int gcol = wc + j * 16 + lr;
                float b = bias[gcol];
#pragma unroll
                for (int r = 0; r < 4; r++) {
                    int grow = m0 + wr + i * 16 + half * 4 + r;
                    Cf[(size_t)(rowOff + grow) * DHEAD + gcol] = acc[i][j][r] + b;
                }
            }
    }
}

// ---------------------------------------------------------------------------
// aggregate: segment softmax + aggregate + bias + ELU -> y bf16 [CHUNK_N,512]
// ONE WAVE PER NODE covering all 4 heads. Lane l holds STORAGE elements
// 8l..8l+7 of the permuted 512-row (uint4); head h = l>>4 still valid since
// the permutation is within-head. bias_g is stored permuted to match.
// ---------------------------------------------------------------------------
__launch_bounds__(256)
__global__ void aggregate(const unsigned short* __restrict__ xw,
                          const float* __restrict__ a_src, const float* __restrict__ a_dst,
                          const int* __restrict__ off, const int* __restrict__ deg,
                          const int* __restrict__ csr, const float* __restrict__ bias_g,
                          unsigned short* __restrict__ y, int nodeBase) {
    int local = blockIdx.x * 4 + (threadIdx.x >> 6);   // node within chunk
    int node = nodeBase + local;
    int l = threadIdx.x & 63;
    int h = l >> 4;                    // head of this lane's 8 elements
    int ebase = l * 8;                 // element offset in the 512-row
    int o = off[node], dn = deg[node];
    float ad = a_dst[node * HEADS + h];

    float acc[8];
    float denom;
    {   // self loop
        float w = __expf(lrelu(a_src[node * HEADS + h] + ad));
        uint4 q = *(const uint4*)&xw[(size_t)node * HD + ebase];
        const unsigned short* u = (const unsigned short*)&q;
        denom = w;
#pragma unroll
        for (int k = 0; k < 8; k++) acc[k] = w * bf2f(u[k]);
    }

    for (int e0 = 0; e0 < dn; e0 += 8) {
        int   idx[8];
        float as[8];
        uint4 px[8];
#pragma unroll
        for (int b = 0; b < 8; b++)
            idx[b] = (e0 + b < dn) ? csr[o + e0 + b] : node;
#pragma unroll
        for (int b = 0; b < 8; b++)
            as[b] = a_src[idx[b] * HEADS + h];
#pragma unroll
        for (int b = 0; b < 8; b++)
            px[b] = *(const uint4*)&xw[(size_t)idx[b] * HD + ebase];
#pragma unroll
        for (int b = 0; b < 8; b++) {
            float w = (e0 + b < dn) ? __expf(lrelu(as[b] + ad)) : 0.0f;
            denom += w;
            const unsigned short* u = (const unsigned short*)&px[b];
#pragma unroll
            for (int k = 0; k < 8; k++) acc[k] += w * bf2f(u[k]);
        }
    }

    float inv = 1.0f / (denom + 1e-16f);
    unsigned short outp[8];
#pragma unroll
    for (int k = 0; k < 8; k++) {
        float v = acc[k] * inv + bias_g[ebase + k];
        v = v > 0.f ? v : (__expf(v) - 1.0f);   // ELU
        outp[k] = f2bf(v);
    }
    *(uint4*)&y[(size_t)local * HD + ebase] = *(const uint4*)outp;
}

extern "C" void kernel_launch(void* const* d_in, const int* in_sizes, int n_in,
                              void* d_out, int out_size, void* d_ws, size_t ws_size,
                              hipStream_t stream) {
    char* ws = (char*)d_ws;
    size_t wsoff = 0;
    auto alloc = [&](size_t bytes) -> char* {
        char* p = ws + wsoff;
        wsoff += (bytes + 255) & ~(size_t)255;
        return p;
    };

    int*            flags  = (int*)           alloc(256);
    unsigned short* WT1    = (unsigned short*)alloc((size_t)HD * C_IN * 2);        // 128 KB
    unsigned short* WT2    = (unsigned short*)alloc((size_t)DHEAD * HD * 2);       // 128 KB
    float*          attS   = (float*)         alloc(HD * 4);
    float*          attD   = (float*)         alloc(HD * 4);
    float*          biasG  = (float*)         alloc(HD * 4);
    float*          bLin   = (float*)         alloc(DHEAD * 4);
    int*            src32  = (int*)           alloc((size_t)E_EDGES * 4);          // 2.6 MB
    int*            dst32  = (int*)           alloc((size_t)E_EDGES * 4);          // 2.6 MB
    int*            deg    = (int*)           alloc((size_t)N_NODES * 4);          // 0.5 MB
    int*            offv   = (int*)           alloc((size_t)(N_NODES + 1) * 4);    // 0.5 MB
    int*            cursor = (int*)           alloc((size_t)N_NODES * 4);          // 0.5 MB
    int*            csr    = (int*)           alloc((size_t)E_EDGES * 4);          // 2.6 MB
    int*            bsums  = (int*)           alloc((size_t)SCAN_B * 4);           // 2 KB
    float*          aSrc   = (float*)         alloc((size_t)N_NODES * HEADS * 4);  // 2.1 MB
    float*          aDst   = (float*)         alloc((size_t)N_NODES * HEADS * 4);  // 2.1 MB
    unsigned short* xw     = (unsigned short*)alloc((size_t)N_NODES * HD * 2);     // 134.2 MB
    unsigned short* ychunk = (unsigned short*)alloc((size_t)CHUNK_N * HD * 2);     // 33.6 MB
    // total ws use ~182 MB

    const void* patches = d_in[0];
    const void* edges   = d_in[1];
    const void* Wgat    = d_in[2];
    const void* attSrcI = d_in[3];
    const void* attDstI = d_in[4];
    const void* biasGI  = d_in[5];
    const void* WlinI   = d_in[6];
    const void* bLinI   = d_in[7];

    detect_kernel<<<1, 64, 0, stream>>>((const unsigned int*)patches,
                                        (const unsigned int*)edges, flags);

    conv_w1<<<(HD * C_IN) / 256, 256, 0, stream>>>(Wgat, WT1, flags);
    conv_w2<<<(DHEAD * HD) / 256, 256, 0, stream>>>(WlinI, WT2, flags);
    conv_small<<<7, 256, 0, stream>>>(attSrcI, attDstI, biasGI, bLinI,
                                      attS, attD, biasG, bLin, flags);

    zero_deg<<<N_NODES / 256, 256, 0, stream>>>(deg);
    conv_edges_hist<<<(2 * E_EDGES) / 256, 256, 0, stream>>>(edges, src32, dst32, deg, flags);
    scan_local<<<SCAN_B, 256, 0, stream>>>(deg, offv, bsums);
    scan_bsums<<<1, SCAN_B, 0, stream>>>(bsums);
    scan_apply<<<SCAN_B, 256, 0, stream>>>(offv, bsums, cursor);
    scatter_kernel<<<E_EDGES / 256, 256, 0, stream>>>(src32, dst32, cursor, csr);

    // xw = x @ W_gat + fused a_src/a_dst
    gemm1_fused<<<N_NODES / 64, 256, 0, stream>>>(
        patches, WT1, attS, attD, xw, aSrc, aDst, flags);

    // chunked: aggregate -> ychunk -> gemm2 -> d_out rows
    for (int c = 0; c < NCHUNK; c++) {
        int base = c * CHUNK_N;
        aggregate<<<CHUNK_N / 4, 256, 0, stream>>>(xw, aSrc, aDst, offv, deg, csr,
                                                   biasG, ychunk, base);
        gemm2<<<CHUNK_N / 64, 256, 0, stream>>>(
            ychunk, WT2, bLin, (unsigned short*)d_out, (float*)d_out, flags, base);
    }
}

// Round 7
// 387.377 us; speedup vs baseline: 1.5690x; 1.1566x over previous
//
#include <hip/hip_runtime.h>
#include <hip/hip_bf16.h>
#include <stdint.h>

// Problem constants (from reference): B=256,P=512,V=8,L=16 -> N=131072, C=128
#define N_NODES 131072
#define C_IN    128
#define HEADS   4
#define DHEAD   128
#define HD      512        // HEADS*DHEAD
#define E_EDGES 655360     // N*5
#define NEG_SLOPE 0.2f
#define SCAN_B  (N_NODES / 256)      // 512 scan blocks
#define MT      32                   // nodes per fused agg+gemm2 block

typedef short bf16x8 __attribute__((ext_vector_type(8)));
typedef float f32x4  __attribute__((ext_vector_type(4)));

__device__ __forceinline__ float bf2f(unsigned short u) {
    unsigned int x = ((unsigned int)u) << 16;
    return __builtin_bit_cast(float, x);
}
__device__ __forceinline__ unsigned short f2bf(float f) {
    unsigned int u = __builtin_bit_cast(unsigned int, f);
    unsigned int r = u + 0x7FFFu + ((u >> 16) & 1u);   // RNE
    return (unsigned short)(r >> 16);
}
__device__ __forceinline__ float lrelu(float v) {
    return v > 0.0f ? v : NEG_SLOPE * v;
}

// xw/y-rows/bias_g/WT2-K live in a PERMUTED 512-col layout (within-head, so
// head id of storage index s is still s>>7). Storage s (per head, 7 bits:
// P[2] half[2] b[1] e[2]) <-> logical col (2P+b)*16 + half*4 + e. This makes
// gemm1's pass-pair uint4 stores land as 64 B contiguous row-chunks
// (WRITE_SIZE 223->135 MB, verified R5). aggregate is elementwise-per-head:
// unchanged. gemm2 contracts over K with BOTH operands permuted identically.
__device__ __forceinline__ int perm512(int s) {
    int w = s >> 7, r = s & 127;
    int P = r >> 5, half = (r >> 3) & 3, b = (r >> 2) & 1, e = r & 3;
    return w * 128 + (2 * P + b) * 16 + half * 4 + e;
}

// ---------------------------------------------------------------------------
// dtype detection: flags[0]=1 if float inputs are bf16 (else fp32);
//                  flags[1]=1 if edge_index is int64 (else int32)
// ---------------------------------------------------------------------------
__global__ void detect_kernel(const unsigned int* p_f, const unsigned int* p_i, int* flags) {
    int lane = threadIdx.x;   // 64 threads
    int cnt = 0;
#pragma unroll
    for (int r = 0; r < 4; r++) {
        unsigned int e = (p_f[lane + 64 * r] >> 7) & 0xFFu;
        cnt += (e >= 110u && e <= 137u) ? 1 : 0;
    }
    int z = 0;
#pragma unroll
    for (int r = 0; r < 2; r++) {
        z += (p_i[2 * (lane + 64 * r) + 1] == 0u) ? 1 : 0;
    }
#pragma unroll
    for (int o = 1; o < 64; o <<= 1) {
        cnt += __shfl_xor(cnt, o, 64);
        z   += __shfl_xor(z, o, 64);
    }
    if (lane == 0) {
        flags[0] = (cnt >= 128) ? 1 : 0;   // 256 bf16 samples, expect ~240 if bf16
        flags[1] = (z == 128) ? 1 : 0;     // all int64 high words zero
    }
}

// W_gat [128,512] -> WT1 in FRAGMENT-MAJOR layout for gemm1's per-wave B regs:
// flat idx = (((g*4 + kk)*64) + l)*8 + e  maps element
//   col = g*16 + (l&15), k = kk*32 + (l>>4)*8 + e   (g=col-group 0..31)
// so frag (g,kk) is 64 lanes x 16 B contiguous -> one coalesced 1 KB load.
__global__ void conv_w1(const void* in, unsigned short* out, const int* flags) {
    int idx = blockIdx.x * blockDim.x + threadIdx.x;   // 65536
    int e = idx & 7;
    int l = (idx >> 3) & 63;
    int t = idx >> 9;                  // g*4 + kk, 0..127
    int kk = t & 3, g = t >> 2;
    int col = g * 16 + (l & 15);
    int k = kk * 32 + (l >> 4) * 8 + e;
    float v = flags[0] ? bf2f(((const unsigned short*)in)[k * HD + col])
                       : ((const float*)in)[k * HD + col];
    out[idx] = f2bf(v);
}

// W_lin [512,128] -> WT2 in FRAGMENT-MAJOR layout for the fused gemm2 phase:
// flat idx = ((jg*16 + kk)*64 + l)*8 + e maps element
//   col = jg*16 + (l&15)                   (jg = out-col group 0..7)
//   storage_k = kk*32 + (l>>4)*8 + e, logical k = perm512(storage_k)
// so frag (jg,kk) is 64 lanes x 16 B contiguous -> one coalesced 1 KB load,
// and the K dim matches the permuted y-row storage order.
__global__ void conv_w2(const void* in, unsigned short* out, const int* flags) {
    int idx = blockIdx.x * blockDim.x + threadIdx.x;   // 65536
    int e = idx & 7;
    int l = (idx >> 3) & 63;
    int f = idx >> 9;                  // jg*16 + kk, 0..127
    int kk = f & 15, jg = f >> 4;
    int col = jg * 16 + (l & 15);
    int sk = kk * 32 + (l >> 4) * 8 + e;
    int k = perm512(sk);
    float v = flags[0] ? bf2f(((const unsigned short*)in)[k * DHEAD + col])
                       : ((const float*)in)[k * DHEAD + col];
    out[idx] = f2bf(v);
}

// att_src/att_dst (512 each, LOGICAL order) + bias_gat (512, PERMUTED order)
// + b_lin (128, logical) -> fp32
__global__ void conv_small(const void* as, const void* ad, const void* bg, const void* bl,
                           float* att_s, float* att_d, float* bias_g, float* b_lin,
                           const int* flags) {
    int i = blockIdx.x * blockDim.x + threadIdx.x;
    bool bf = flags[0] != 0;
    if (i < 512) {
        att_s[i] = bf ? bf2f(((const unsigned short*)as)[i]) : ((const float*)as)[i];
    } else if (i < 1024) {
        int j = i - 512;
        att_d[j] = bf ? bf2f(((const unsigned short*)ad)[j]) : ((const float*)ad)[j];
    } else if (i < 1536) {
        int j = perm512(i - 1024);     // bias stored permuted
        bias_g[i - 1024] = bf ? bf2f(((const unsigned short*)bg)[j]) : ((const float*)bg)[j];
    } else if (i < 1664) {
        int j = i - 1536;
        b_lin[j] = bf ? bf2f(((const unsigned short*)bl)[j]) : ((const float*)bl)[j];
    }
}

// edge_index [2,E] -> src32 [E], dst32 [E]; fused degree histogram
__global__ void conv_edges_hist(const void* in, int* src32, int* dst32, int* deg,
                                const int* flags) {
    int i = blockIdx.x * blockDim.x + threadIdx.x;
    if (i >= 2 * E_EDGES) return;
    int v = flags[1] ? (int)((const long long*)in)[i] : ((const int*)in)[i];
    if (i < E_EDGES) {
        src32[i] = v;
    } else {
        dst32[i - E_EDGES] = v;
        atomicAdd(&deg[v], 1);
    }
}

__global__ void zero_deg(int* deg) {
    int i = blockIdx.x * blockDim.x + threadIdx.x;
    deg[i] = 0;
}

// ---------------------------------------------------------------------------
// Hierarchical exclusive scan of deg[N] -> offv[N] (+cursor copy).
// ---------------------------------------------------------------------------
__global__ void scan_local(const int* __restrict__ deg, int* __restrict__ offv,
                           int* __restrict__ bsums) {
    __shared__ int tmp[256];
    int t = threadIdx.x;
    int g = blockIdx.x * 256 + t;
    int v = deg[g];
    tmp[t] = v;
    __syncthreads();
#pragma unroll
    for (int d = 1; d < 256; d <<= 1) {
        int x = (t >= d) ? tmp[t - d] : 0;
        __syncthreads();
        tmp[t] += x;
        __syncthreads();
    }
    offv[g] = tmp[t] - v;              // exclusive within block
    if (t == 255) bsums[blockIdx.x] = tmp[t];
}

__global__ void scan_bsums(int* bsums) {
    __shared__ int tmp[SCAN_B];
    int t = threadIdx.x;               // 512 threads
    int v = bsums[t];
    tmp[t] = v;
    __syncthreads();
#pragma unroll
    for (int d = 1; d < SCAN_B; d <<= 1) {
        int x = (t >= d) ? tmp[t - d] : 0;
        __syncthreads();
        tmp[t] += x;
        __syncthreads();
    }
    bsums[t] = tmp[t] - v;             // exclusive block bases
}

__global__ void scan_apply(int* __restrict__ offv, const int* __restrict__ bsums,
                           int* __restrict__ cursor) {
    int g = blockIdx.x * 256 + threadIdx.x;
    int v = offv[g] + bsums[blockIdx.x];
    offv[g] = v;
    cursor[g] = v;
}

__global__ void scatter_kernel(const int* src32, const int* dst32, int* cursor, int* csr) {
    int i = blockIdx.x * blockDim.x + threadIdx.x;
    int d = dst32[i];
    int pos = atomicAdd(&cursor[d], 1);
    csr[pos] = src32[i];
}

// ---------------------------------------------------------------------------
// gemm1 fused v6 (UNCHANGED from R6 best: 68us): xw = x @ W_gat + att logits.
// History: v1 85 (barrier/occ), v2 145 (strided global B latency), v3 90
// (WRITE amplification 223MB), v4 204 (launch_bounds VGPR cap -> spill),
// v5 74.8 (pass-pair permuted uint4 stores: WRITE 135MB), v6 68 (A hoisted
// to regs, zero LDS reads in pass loop; VGPR 164).
// ---------------------------------------------------------------------------
__launch_bounds__(256)
__global__ void gemm1_fused(const void* __restrict__ Ain,
                            const unsigned short* __restrict__ BT2,  // frag-major WT1
                            const float* __restrict__ attS, const float* __restrict__ attD,
                            unsigned short* __restrict__ xw,
                            float* __restrict__ aSrc, float* __restrict__ aDst,
                            const int* __restrict__ flags) {
    __shared__ unsigned short lA[64 * 136];   // 17408 B
    int tid = threadIdx.x;
    int m0 = blockIdx.x * 64;

    // stage A row-strip (64 x 128), fp32->bf16 if needed
    if (flags[0] == 0) {
        const float* Af = (const float*)Ain;
#pragma unroll
        for (int p = 0; p < 8; p++) {
            int l = p * 256 + tid;                  // 2048 float4 chunks
            int r = l >> 5, c = (l & 31) * 4;
            float4 f = *(const float4*)&Af[(size_t)(m0 + r) * C_IN + c];
            unsigned short t4[4] = {f2bf(f.x), f2bf(f.y), f2bf(f.z), f2bf(f.w)};
            *(uint2*)&lA[r * 136 + c] = *(const uint2*)t4;
        }
    } else {
        const unsigned short* Ab = (const unsigned short*)Ain;
#pragma unroll
        for (int p = 0; p < 4; p++) {
            int l = p * 256 + tid;                  // 1024 uint4 chunks
            int r = l >> 4, c = (l & 15) * 8;
            *(uint4*)&lA[r * 136 + c] = *(const uint4*)&Ab[(size_t)(m0 + r) * C_IN + c];
        }
    }
    __syncthreads();   // the ONLY barrier

    int w = tid >> 6, lane = tid & 63;   // wave w = head w, 64 rows x 128 cols
    int lr = lane & 15, half = lane >> 4;

    // hoist ALL A fragments for this wave into registers (16 bf16x8 = 64 VGPR)
    bf16x8 afr[4][4];
#pragma unroll
    for (int i = 0; i < 4; i++)
#pragma unroll
        for (int kk = 0; kk < 4; kk++)
            afr[i][kk] = *(const bf16x8*)&lA[(i * 16 + lr) * 136 + kk * 32 + half * 8];

    const float4* attS4 = (const float4*)attS;
    const float4* attD4 = (const float4*)attD;

    float dS[4], dD[4];
#pragma unroll
    for (int i = 0; i < 4; i++) { dS[i] = 0.f; dD[i] = 0.f; }

    // register double-buffer for B fragments (frag-major: coalesced 1 KB/load)
    bf16x8 bbuf[2][4];
#pragma unroll
    for (int kk = 0; kk < 4; kk++)
        bbuf[0][kk] = *(const bf16x8*)&BT2[(((w * 8 + 0) * 4 + kk) << 9) + (lane << 3)];

    uint2 pk_lo[4];    // packed bf16 of the even pass, flushed at the odd pass

#pragma unroll
    for (int p = 0; p < 8; p++) {       // 8 col-passes of 16 within head w
        int cur = p & 1;
        if (p < 7) {
#pragma unroll
            for (int kk = 0; kk < 4; kk++)
                bbuf[cur ^ 1][kk] =
                    *(const bf16x8*)&BT2[(((w * 8 + p + 1) * 4 + kk) << 9) + (lane << 3)];
        }

        f32x4 acc[4];
#pragma unroll
        for (int i = 0; i < 4; i++) acc[i] = (f32x4){0.f, 0.f, 0.f, 0.f};

#pragma unroll
        for (int kk = 0; kk < 4; kk++)
#pragma unroll
            for (int i = 0; i < 4; i++)
                acc[i] = __builtin_amdgcn_mfma_f32_16x16x32_bf16(bbuf[cur][kk], afr[i][kk], acc[i], 0, 0, 0);

        // attention dots use LOGICAL cols p*16 + half*4 + {0..3}
        float4 s4 = attS4[w * 32 + p * 4 + half];
        float4 d4 = attD4[w * 32 + p * 4 + half];
#pragma unroll
        for (int i = 0; i < 4; i++) {
            dS[i] += acc[i][0] * s4.x + acc[i][1] * s4.y + acc[i][2] * s4.z + acc[i][3] * s4.w;
            dD[i] += acc[i][0] * d4.x + acc[i][1] * d4.y + acc[i][2] * d4.z + acc[i][3] * d4.w;
        }

        if ((p & 1) == 0) {
            // even pass: pack and hold
#pragma unroll
            for (int i = 0; i < 4; i++) {
                pk_lo[i].x = (unsigned int)f2bf(acc[i][0]) | ((unsigned int)f2bf(acc[i][1]) << 16);
                pk_lo[i].y = (unsigned int)f2bf(acc[i][2]) | ((unsigned int)f2bf(acc[i][3]) << 16);
            }
        } else {
            // odd pass: store pass-pair as uint4 into permuted layout.
            int P = p >> 1;
#pragma unroll
            for (int i = 0; i < 4; i++) {
                uint4 q;
                q.x = pk_lo[i].x;
                q.y = pk_lo[i].y;
                q.z = (unsigned int)f2bf(acc[i][0]) | ((unsigned int)f2bf(acc[i][1]) << 16);
                q.w = (unsigned int)f2bf(acc[i][2]) | ((unsigned int)f2bf(acc[i][3]) << 16);
                *(uint4*)&xw[(size_t)(m0 + i * 16 + lr) * HD + w * 128 + P * 32 + half * 8] = q;
            }
        }
    }

    // per-head attention-dot reduce over the 4 half-groups
#pragma unroll
    for (int i = 0; i < 4; i++) {
        float ps = dS[i], pd = dD[i];
        ps += __shfl_xor(ps, 16, 64);
        ps += __shfl_xor(ps, 32, 64);
        pd += __shfl_xor(pd, 16, 64);
        pd += __shfl_xor(pd, 32, 64);
        if (half == 0) {
            aSrc[(size_t)(m0 + i * 16 + lr) * HEADS + w] = ps;
            aDst[(size_t)(m0 + i * 16 + lr) * HEADS + w] = pd;
        }
    }
}

// ---------------------------------------------------------------------------
// FUSED aggregate + gemm2: per block of MT=32 nodes,
//   phase 1: segment softmax + aggregate + bias + ELU -> y rows in LDS (bf16,
//            permuted col order; identical arithmetic to the old aggregate)
//   phase 2: out = y @ W_lin + b_lin via MFMA, A from LDS, B = frag-major WT2
// Removes the y HBM round-trip (134 MB write + 134 MB read) and the ychunk
// buffer + 8 dispatches.
// LDS y-tile stride 520 shorts (same mod-32 bank pattern as the proven 136).
// ---------------------------------------------------------------------------
__launch_bounds__(256)
__global__ void agg_gemm2(const unsigned short* __restrict__ xw,
                          const float* __restrict__ a_src, const float* __restrict__ a_dst,
                          const int* __restrict__ off, const int* __restrict__ deg,
                          const int* __restrict__ csr, const float* __restrict__ bias_g,
                          const unsigned short* __restrict__ BT2f,  // frag-major WT2
                          const float* __restrict__ b_lin,
                          unsigned short* __restrict__ Cbf, float* __restrict__ Cf,
                          const int* __restrict__ flags) {
    __shared__ unsigned short yt[MT * 520];   // 33280 B
    int tid = threadIdx.x;
    int m0 = blockIdx.x * MT;
    int w = tid >> 6, l = tid & 63;
    int h = l >> 4;                    // head of this lane's 8 elements
    int ebase = l * 8;                 // storage elem offset in the 512-row

    // ---------------- phase 1: gather/softmax 8 nodes per wave --------------
    for (int g = 0; g < MT / 4; g++) {
        int row = w * (MT / 4) + g;
        int node = m0 + row;
        int o = off[node], dn = deg[node];
        float ad = a_dst[node * HEADS + h];

        float acc[8];
        float denom;
        {   // self loop
            float wgt = __expf(lrelu(a_src[node * HEADS + h] + ad));
            uint4 q = *(const uint4*)&xw[(size_t)node * HD + ebase];
            const unsigned short* u = (const unsigned short*)&q;
            denom = wgt;
#pragma unroll
            for (int k = 0; k < 8; k++) acc[k] = wgt * bf2f(u[k]);
        }

        for (int e0 = 0; e0 < dn; e0 += 8) {
            int   idx[8];
            float as[8];
            uint4 px[8];
#pragma unroll
            for (int b = 0; b < 8; b++)
                idx[b] = (e0 + b < dn) ? csr[o + e0 + b] : node;
#pragma unroll
            for (int b = 0; b < 8; b++)
                as[b] = a_src[idx[b] * HEADS + h];
#pragma unroll
            for (int b = 0; b < 8; b++)
                px[b] = *(const uint4*)&xw[(size_t)idx[b] * HD + ebase];
#pragma unroll
            for (int b = 0; b < 8; b++) {
                float wgt = (e0 + b < dn) ? __expf(lrelu(as[b] + ad)) : 0.0f;
                denom += wgt;
                const unsigned short* u = (const unsigned short*)&px[b];
#pragma unroll
                for (int k = 0; k < 8; k++) acc[k] += wgt * bf2f(u[k]);
            }
        }

        float inv = 1.0f / (denom + 1e-16f);
        unsigned short outp[8];
#pragma unroll
        for (int k = 0; k < 8; k++) {
            float v = acc[k] * inv + bias_g[ebase + k];
            v = v > 0.f ? v : (__expf(v) - 1.0f);   // ELU
            outp[k] = f2bf(v);
        }
        *(uint4*)&yt[row * 520 + ebase] = *(const uint4*)outp;
    }
    __syncthreads();

    // ---------------- phase 2: 32x512 @ 512x128 MFMA ------------------------
    int lr = l & 15, half = l >> 4;
    f32x4 acc2[2][2];
#pragma unroll
    for (int i = 0; i < 2; i++)
#pragma unroll
        for (int j = 0; j < 2; j++) acc2[i][j] = (f32x4){0.f, 0.f, 0.f, 0.f};

    // B frags (frag-major WT2): frag (jg,kk) = 64 lanes x 16 B contiguous.
    // wave w covers out-col groups jg = 2w, 2w+1. Double-buffered over kk.
    bf16x8 bb[2][2];
#pragma unroll
    for (int j = 0; j < 2; j++)
        bb[0][j] = *(const bf16x8*)&BT2f[((((w * 2 + j) * 16 + 0) * 64 + l) << 3)];

    for (int kk = 0; kk < 16; kk++) {
        int cur = kk & 1;
        if (kk < 15) {
#pragma unroll
            for (int j = 0; j < 2; j++)
                bb[cur ^ 1][j] = *(const bf16x8*)&BT2f[((((w * 2 + j) * 16 + kk + 1) * 64 + l) << 3)];
        }
        bf16x8 af0 = *(const bf16x8*)&yt[(lr) * 520 + kk * 32 + half * 8];
        bf16x8 af1 = *(const bf16x8*)&yt[(16 + lr) * 520 + kk * 32 + half * 8];
        acc2[0][0] = __builtin_amdgcn_mfma_f32_16x16x32_bf16(af0, bb[cur][0], acc2[0][0], 0, 0, 0);
        acc2[0][1] = __builtin_amdgcn_mfma_f32_16x16x32_bf16(af0, bb[cur][1], acc2[0][1], 0, 0, 0);
        acc2[1][0] = __builtin_amdgcn_mfma_f32_16x16x32_bf16(af1, bb[cur][0], acc2[1][0], 0, 0, 0);
        acc2[1][1] = __builtin_amdgcn_mfma_f32_16x16x32_bf16(af1, bb[cur][1], acc2[1][1], 0, 0, 0);
    }

    // epilogue: D col = lane&15 (out col gcol), row = half*4 + r (A dim)
    if (flags[0] != 0) {
        __syncthreads();   // all yt reads done before reuse as staging
#pragma unroll
        for (int i = 0; i < 2; i++)
#pragma unroll
            for (int j = 0; j < 2; j++) {
                int gcol = (w * 2 + j) * 16 + lr;
                float b = b_lin[gcol];
#pragma unroll
                for (int r = 0; r < 4; r++)
                    yt[(i * 16 + half * 4 + r) * 136 + gcol] = f2bf(acc2[i][j][r] + b);
            }
        __syncthreads();
#pragma unroll
        for (int p = 0; p < 2; p++) {
            int ln = p * 256 + tid;            // 512 uint4 chunks (32 rows x 16)
            int r = ln >> 4, c = (ln & 15) * 8;
            *(uint4*)&Cbf[(size_t)(m0 + r) * DHEAD + c] = *(const uint4*)&yt[r * 136 + c];
        }
    } else {
#pragma unroll
        for (int i = 0; i < 2; i++)
#pragma unroll
            for (int j = 0; j < 2; j++) {
                int gcol = (w * 2 + j) * 16 + lr;
                float b = b_lin[gcol];
#pragma unroll
                for (int r = 0; r < 4; r++) {
                    int grow = m0 + i * 16 + half * 4 + r;
                    Cf[(size_t)grow * DHEAD + gcol] = acc2[i][j][r] + b;
                }
            }
    }
}

extern "C" void kernel_launch(void* const* d_in, const int* in_sizes, int n_in,
                              void* d_out, int out_size, void* d_ws, size_t ws_size,
                              hipStream_t stream) {
    char* ws = (char*)d_ws;
    size_t wsoff = 0;
    auto alloc = [&](size_t bytes) -> char* {
        char* p = ws + wsoff;
        wsoff += (bytes + 255) & ~(size_t)255;
        return p;
    };

    int*            flags  = (int*)           alloc(256);
    unsigned short* WT1    = (unsigned short*)alloc((size_t)HD * C_IN * 2);        // 128 KB
    unsigned short* WT2    = (unsigned short*)alloc((size_t)DHEAD * HD * 2);       // 128 KB
    float*          attS   = (float*)         alloc(HD * 4);
    float*          attD   = (float*)         alloc(HD * 4);
    float*          biasG  = (float*)         alloc(HD * 4);
    float*          bLin   = (float*)         alloc(DHEAD * 4);
    int*            src32  = (int*)           alloc((size_t)E_EDGES * 4);          // 2.6 MB
    int*            dst32  = (int*)           alloc((size_t)E_EDGES * 4);          // 2.6 MB
    int*            deg    = (int*)           alloc((size_t)N_NODES * 4);          // 0.5 MB
    int*            offv   = (int*)           alloc((size_t)(N_NODES + 1) * 4);    // 0.5 MB
    int*            cursor = (int*)           alloc((size_t)N_NODES * 4);          // 0.5 MB
    int*            csr    = (int*)           alloc((size_t)E_EDGES * 4);          // 2.6 MB
    int*            bsums  = (int*)           alloc((size_t)SCAN_B * 4);           // 2 KB
    float*          aSrc   = (float*)         alloc((size_t)N_NODES * HEADS * 4);  // 2.1 MB
    float*          aDst   = (float*)         alloc((size_t)N_NODES * HEADS * 4);  // 2.1 MB
    unsigned short* xw     = (unsigned short*)alloc((size_t)N_NODES * HD * 2);     // 134.2 MB
    // total ws use ~148 MB (ychunk eliminated by the fusion)

    const void* patches = d_in[0];
    const void* edges   = d_in[1];
    const void* Wgat    = d_in[2];
    const void* attSrcI = d_in[3];
    const void* attDstI = d_in[4];
    const void* biasGI  = d_in[5];
    const void* WlinI   = d_in[6];
    const void* bLinI   = d_in[7];

    detect_kernel<<<1, 64, 0, stream>>>((const unsigned int*)patches,
                                        (const unsigned int*)edges, flags);

    conv_w1<<<(HD * C_IN) / 256, 256, 0, stream>>>(Wgat, WT1, flags);
    conv_w2<<<(DHEAD * HD) / 256, 256, 0, stream>>>(WlinI, WT2, flags);
    conv_small<<<7, 256, 0, stream>>>(attSrcI, attDstI, biasGI, bLinI,
                                      attS, attD, biasG, bLin, flags);

    zero_deg<<<N_NODES / 256, 256, 0, stream>>>(deg);
    conv_edges_hist<<<(2 * E_EDGES) / 256, 256, 0, stream>>>(edges, src32, dst32, deg, flags);
    scan_local<<<SCAN_B, 256, 0, stream>>>(deg, offv, bsums);
    scan_bsums<<<1, SCAN_B, 0, stream>>>(bsums);
    scan_apply<<<SCAN_B, 256, 0, stream>>>(offv, bsums, cursor);
    scatter_kernel<<<E_EDGES / 256, 256, 0, stream>>>(src32, dst32, cursor, csr);

    // xw = x @ W_gat + fused a_src/a_dst
    gemm1_fused<<<N_NODES / 64, 256, 0, stream>>>(
        patches, WT1, attS, attD, xw, aSrc, aDst, flags);

    // fused aggregate + gemm2 -> d_out (single dispatch, no y round-trip)
    agg_gemm2<<<N_NODES / MT, 256, 0, stream>>>(
        xw, aSrc, aDst, offv, deg, csr, biasG, WT2, bLin,
        (unsigned short*)d_out, (float*)d_out, flags);
}